// Round 1
// baseline (4775.352 us; speedup 1.0000x reference)
//
#include <hip/hip_runtime.h>
#include <math.h>

// ---------------- problem constants ----------------
constexpr int NB = 32;    // B
constexpr int NM = 64;    // M
constexpr int NNV = 65;   // NV
constexpr int NH = 960;   // H
constexpr int ND = 480;   // D
constexpr float ATT_SCALE = 0.045643546458763842f;  // D^-0.5

// fold-buffer offsets (floats). P blocks always strided for O=3.
constexpr int OF_Pq = 0;              // 3 parts x (3*480)
constexpr int OF_cq = 4320;           // 3 parts x 480
constexpr int OF_Q2 = 5760;           // 3 parts x (3*480)
constexpr int OF_V2 = OF_Q2 + 2*1440; // 8640
constexpr int OF_dq = 10080;          // 3 parts x 480
constexpr int OF_dv = OF_dq + 2*480;  // 11040
constexpr int OF_S  = 11520;          // 9  (S2 at +16)
constexpr int OF_u  = 11529;          // 3
constexpr int OF_r  = 11532;          // 3
constexpr int OF_w  = 11535;          // 1
constexpr int FOLD_SZ = 11552;

__device__ __forceinline__ float wave_max(float v) {
#pragma unroll
  for (int d = 32; d; d >>= 1) v = fmaxf(v, __shfl_xor(v, d));
  return v;
}
__device__ __forceinline__ float wave_sum(float v) {
#pragma unroll
  for (int d = 32; d; d >>= 1) v += __shfl_xor(v, d);
  return v;
}

// C[r,n] = sum_h X[row(r),h]*W[n,h] + bias[n]; row(r) = b*xbs + (x0+rr)*K, r=b*rpb+rr
__global__ __launch_bounds__(256) void k_proj(
    const float* __restrict__ X, const float* __restrict__ W,
    const float* __restrict__ bias, float* __restrict__ C,
    int R, int N, int K, int rpb, int x0, int xbs)
{
  __shared__ float As[16][65];
  __shared__ float Bs[16][65];
  const int tid = threadIdx.x;
  const int tm = tid >> 4, tn = tid & 15;
  const int m0 = blockIdx.y * 64, n0 = blockIdx.x * 64;
  float acc[4][4] = {};
  for (int k0 = 0; k0 < K; k0 += 16) {
    for (int i = tid; i < 1024; i += 256) {
      int mm = i >> 4, kk = i & 15;
      int r = m0 + mm;
      float v = 0.f;
      if (r < R) {
        int b = r / rpb, rr = r - b * rpb;
        v = X[(size_t)b * xbs + (size_t)(x0 + rr) * K + k0 + kk];
      }
      As[kk][mm] = v;
    }
    for (int i = tid; i < 1024; i += 256) {
      int nn = i >> 4, kk = i & 15;
      int n = n0 + nn;
      Bs[kk][nn] = (n < N) ? W[(size_t)n * K + k0 + kk] : 0.f;
    }
    __syncthreads();
#pragma unroll
    for (int kk = 0; kk < 16; ++kk) {
      float a[4], bv[4];
#pragma unroll
      for (int i = 0; i < 4; ++i) a[i] = As[kk][tm * 4 + i];
#pragma unroll
      for (int j = 0; j < 4; ++j) bv[j] = Bs[kk][tn * 4 + j];
#pragma unroll
      for (int i = 0; i < 4; ++i)
#pragma unroll
        for (int j = 0; j < 4; ++j) acc[i][j] += a[i] * bv[j];
    }
    __syncthreads();
  }
#pragma unroll
  for (int i = 0; i < 4; ++i) {
    int r = m0 + tm * 4 + i;
    if (r >= R) continue;
#pragma unroll
    for (int j = 0; j < 4; ++j) {
      int n = n0 + tn * 4 + j;
      if (n < N) C[(size_t)r * N + n] = acc[i][j] + bias[n];
    }
  }
}

// tmp[z=b*O+o][m,d2] = sum_d1 Key[b][m,d1] * W[o][d1,d2]   (NN gemm, M=64, K=N=480)
__global__ __launch_bounds__(256) void k_tmp(
    const float* __restrict__ Key, const float* __restrict__ W,
    float* __restrict__ T, int O)
{
  const int z = blockIdx.z;
  const int b = z / O, o = z - b * O;
  const float* A = Key + (size_t)b * NM * ND;
  const float* Bm = W + (size_t)o * ND * ND;
  float* C = T + (size_t)z * NM * ND;
  __shared__ float As[16][65];
  __shared__ float Bs[16][65];
  const int tid = threadIdx.x;
  const int tm = tid >> 4, tn = tid & 15;
  const int n0 = blockIdx.x * 64;
  float acc[4][4] = {};
  for (int k0 = 0; k0 < ND; k0 += 16) {
    for (int i = tid; i < 1024; i += 256) {
      int mm = i >> 4, kk = i & 15;
      As[kk][mm] = A[(size_t)mm * ND + k0 + kk];
    }
    for (int i = tid; i < 1024; i += 256) {
      int nn = i & 63, kk = i >> 6;
      int n = n0 + nn;
      Bs[kk][nn] = (n < ND) ? Bm[(size_t)(k0 + kk) * ND + n] : 0.f;
    }
    __syncthreads();
#pragma unroll
    for (int kk = 0; kk < 16; ++kk) {
      float a[4], bv[4];
#pragma unroll
      for (int i = 0; i < 4; ++i) a[i] = As[kk][tm * 4 + i];
#pragma unroll
      for (int j = 0; j < 4; ++j) bv[j] = Bs[kk][tn * 4 + j];
#pragma unroll
      for (int i = 0; i < 4; ++i)
#pragma unroll
        for (int j = 0; j < 4; ++j) acc[i][j] += a[i] * bv[j];
    }
    __syncthreads();
  }
#pragma unroll
  for (int i = 0; i < 4; ++i) {
    int m = tm * 4 + i;
#pragma unroll
    for (int j = 0; j < 4; ++j) {
      int n = n0 + tn * 4 + j;
      if (n < ND) C[(size_t)m * ND + n] = acc[i][j];
    }
  }
}

// Out[((b*64+m)*NVx+n)*O+o] = tmp[b,o][m,:]·Val[b][n,:] + linK + linV + lb[o]  (x mask if FINAL)
template <int FINAL>
__global__ __launch_bounds__(256) void k_bil(
    const float* __restrict__ T, const float* __restrict__ Val,
    const float* __restrict__ linK, const float* __restrict__ linV,
    const float* __restrict__ lb, const float* __restrict__ km,
    const float* __restrict__ vm, int vmOff, int vmStride,
    float* __restrict__ Out, int NVx, int O)
{
  const int z = blockIdx.z;
  const int b = z / O, o = z - b * O;
  const float* A = T + (size_t)z * NM * ND;
  const float* Bv = Val + (size_t)b * NVx * ND;
  __shared__ float As[16][65];
  __shared__ float Bs[16][65];
  const int tid = threadIdx.x;
  const int tm = tid >> 4, tn = tid & 15;
  const int n0 = blockIdx.x * 64;
  float acc[4][4] = {};
  for (int k0 = 0; k0 < ND; k0 += 16) {
    for (int i = tid; i < 1024; i += 256) {
      int mm = i >> 4, kk = i & 15;
      As[kk][mm] = A[(size_t)mm * ND + k0 + kk];
    }
    for (int i = tid; i < 1024; i += 256) {
      int nn = i >> 4, kk = i & 15;
      int n = n0 + nn;
      Bs[kk][nn] = (n < NVx) ? Bv[(size_t)n * ND + k0 + kk] : 0.f;
    }
    __syncthreads();
#pragma unroll
    for (int kk = 0; kk < 16; ++kk) {
      float a[4], bv[4];
#pragma unroll
      for (int i = 0; i < 4; ++i) a[i] = As[kk][tm * 4 + i];
#pragma unroll
      for (int j = 0; j < 4; ++j) bv[j] = Bs[kk][tn * 4 + j];
#pragma unroll
      for (int i = 0; i < 4; ++i)
#pragma unroll
        for (int j = 0; j < 4; ++j) acc[i][j] += a[i] * bv[j];
    }
    __syncthreads();
  }
#pragma unroll
  for (int i = 0; i < 4; ++i) {
    int m = tm * 4 + i;
#pragma unroll
    for (int j = 0; j < 4; ++j) {
      int n = n0 + tn * 4 + j;
      if (n >= NVx) continue;
      float v = acc[i][j] + linK[((size_t)b * NM + m) * O + o]
                          + linV[((size_t)b * NVx + n) * O + o] + lb[o];
      if (FINAL) v *= km[b * NM + m] * vm[b * vmStride + vmOff + n];
      Out[(((size_t)b * NM + m) * NVx + n) * O + o] = v;
    }
  }
}

// Out[r,o] = X[r,:]·W[o, wOff:wOff+480]
__global__ void k_sproj(const float* __restrict__ X, const float* __restrict__ W,
                        float* __restrict__ Out, int R, int O, int wStride, int wOff)
{
  int idx = blockIdx.x * blockDim.x + threadIdx.x;
  if (idx >= R * O) return;
  int r = idx / O, o = idx - r * O;
  const float* x = X + (size_t)r * ND;
  const float* w = W + (size_t)o * wStride + wOff;
  float acc = 0.f;
  for (int d = 0; d < ND; ++d) acc += x[d] * w[d];
  Out[idx] = acc;
}

// fold stage 1: P_q/P_k/P_v (OxD) and c_q/c_k/c_v (D)
__global__ void k_fold1(const float* __restrict__ fw, const float* __restrict__ fb,
                        const float* __restrict__ qw, const float* __restrict__ qb,
                        float* __restrict__ F, int O)
{
  int t = blockIdx.x * blockDim.x + threadIdx.x;
  if (t >= 3 * ND) return;
  int part = t / ND, c = t - part * ND;
  const float* qrow = qw + (size_t)(part * ND + c) * ND;
  float accP[3] = {0.f, 0.f, 0.f};
  float accC = 0.f;
  for (int d = 0; d < ND; ++d) {
    float q = qrow[d];
    for (int o = 0; o < O; ++o) accP[o] += fw[(size_t)d * O + o] * q;
    accC += fb[d] * q;
  }
  for (int o = 0; o < O; ++o) F[OF_Pq + part * 1440 + o * ND + c] = accP[o];
  F[OF_cq + part * ND + c] = accC + qb[part * ND + c];
}

// fold stage 2: Q2/K2/V2, d_q/d_k/d_v, and S/u/r/w (zero-filled beyond O)
__global__ void k_fold2(const float* __restrict__ qw, const float* __restrict__ qb,
                        float* __restrict__ F, int O)
{
  int t = blockIdx.x * blockDim.x + threadIdx.x;
  if (t < 3 * ND) {
    int part = t / ND, c = t - part * ND;
    const float* qrow = qw + (size_t)(part * ND + c) * ND;
    const float* Pv = F + OF_Pq + 2 * 1440;
    const float* cv = F + OF_cq + 2 * ND;
    float accQ[3] = {0.f, 0.f, 0.f};
    float accD = 0.f;
    for (int d = 0; d < ND; ++d) {
      float q = qrow[d];
      for (int o = 0; o < O; ++o) accQ[o] += Pv[o * ND + d] * q;
      accD += cv[d] * q;
    }
    for (int o = 0; o < O; ++o) F[OF_Q2 + part * 1440 + o * ND + c] = accQ[o];
    F[OF_dq + part * ND + c] = accD + qb[part * ND + c];
  } else if (t < 3 * ND + 16) {
    int s = t - 3 * ND;
    const float* Pq = F + OF_Pq;
    const float* Pk = F + OF_Pq + 1440;
    const float* cq = F + OF_cq;
    const float* ck = F + OF_cq + ND;
    float acc = 0.f;
    if (s < 9) {
      int o = s / 3, op = s % 3;
      bool ok = (o < O) && (op < O);
      if (ok) for (int c = 0; c < ND; ++c) acc += Pq[o * ND + c] * Pk[op * ND + c];
      F[OF_S + s] = ok ? acc : 0.f;
    } else if (s < 12) {
      int o = s - 9; bool ok = o < O;
      if (ok) for (int c = 0; c < ND; ++c) acc += Pq[o * ND + c] * ck[c];
      F[OF_u + o] = ok ? acc : 0.f;
    } else if (s < 15) {
      int o = s - 12; bool ok = o < O;
      if (ok) for (int c = 0; c < ND; ++c) acc += cq[c] * Pk[o * ND + c];
      F[OF_r + o] = ok ? acc : 0.f;
    } else {
      for (int c = 0; c < ND; ++c) acc += cq[c] * ck[c];
      F[OF_w] = acc;
    }
  }
}

// fold stage 3: S2/u2/r2/w2 (at +16 from S/u/r/w)
__global__ void k_fold3(float* __restrict__ F, int O)
{
  int s = threadIdx.x;
  if (s >= 16) return;
  const float* Q2 = F + OF_Q2;
  const float* K2 = F + OF_Q2 + 1440;
  const float* dq = F + OF_dq;
  const float* dk = F + OF_dq + ND;
  float acc = 0.f;
  if (s < 9) {
    int o = s / 3, op = s % 3;
    bool ok = (o < O) && (op < O);
    if (ok) for (int c = 0; c < ND; ++c) acc += Q2[o * ND + c] * K2[op * ND + c];
    F[OF_S + 16 + s] = ok ? acc : 0.f;
  } else if (s < 12) {
    int o = s - 9; bool ok = o < O;
    if (ok) for (int c = 0; c < ND; ++c) acc += Q2[o * ND + c] * dk[c];
    F[OF_u + 16 + o] = ok ? acc : 0.f;
  } else if (s < 15) {
    int o = s - 12; bool ok = o < O;
    if (ok) for (int c = 0; c < ND; ++c) acc += dq[c] * K2[o * ND + c];
    F[OF_r + 16 + o] = ok ? acc : 0.f;
  } else {
    for (int c = 0; c < ND; ++c) acc += dq[c] * dk[c];
    F[OF_w + 16] = acc;
  }
}

// MODE 0: att over NV axis per (b,m); MODE 1: att over M axis per (b,n)
template <int MODE>
__global__ __launch_bounds__(256) void k_att(
    const float* __restrict__ Tsrc, float* __restrict__ Yout,
    const float* __restrict__ F,
    const float* __restrict__ km, const float* __restrict__ vm,
    int vmOff, int vmStride, int NVx, int O)
{
  __shared__ float Ts[NNV][3], STs[NNV][3], hs[NNV], gs[NNV], mk[NNV];
  const int blk = blockIdx.x;
  int b, p, NR;
  if (MODE == 0) { b = blk >> 6; p = blk & 63; NR = NVx; }
  else           { b = blk / NVx; p = blk - b * NVx; NR = NM; }
  const int tid = threadIdx.x;
  const float gm = (MODE == 0) ? km[b * NM + p] : vm[b * vmStride + vmOff + p];
  for (int j = tid; j < NR; j += 256) {
    size_t idx = (MODE == 0) ? (((size_t)b * NM + p) * NVx + j) * O
                             : (((size_t)b * NM + j) * NVx + p) * O;
    Ts[j][0] = Tsrc[idx];
    Ts[j][1] = Tsrc[idx + 1];
    Ts[j][2] = (O == 3) ? Tsrc[idx + 2] : 0.f;
    mk[j] = (MODE == 0) ? vm[b * vmStride + vmOff + j] : km[b * NM + j];
  }
  __syncthreads();
  const float* Sm = F + OF_S + 16 * MODE;
  const float* uv = F + OF_u + 16 * MODE;
  const float* rv = F + OF_r + 16 * MODE;
  const float wc = F[OF_w + 16 * MODE];
  for (int j = tid; j < NR; j += 256) {
    float t0 = Ts[j][0], t1 = Ts[j][1], t2 = Ts[j][2];
    STs[j][0] = t0 * Sm[0] + t1 * Sm[3] + t2 * Sm[6];
    STs[j][1] = t0 * Sm[1] + t1 * Sm[4] + t2 * Sm[7];
    STs[j][2] = t0 * Sm[2] + t1 * Sm[5] + t2 * Sm[8];
    hs[j] = t0 * uv[0] + t1 * uv[1] + t2 * uv[2];
    gs[j] = t0 * rv[0] + t1 * rv[1] + t2 * rv[2];
  }
  __syncthreads();
  const int wv = tid >> 6, lane = tid & 63;
  const bool gz = (gm == 0.f);
  for (int i = wv; i < NR; i += 4) {
    const float qm = mk[i];
    const float st0 = STs[i][0], st1 = STs[i][1], st2 = STs[i][2], hi = hs[i];
    const int j0 = lane, j1 = lane + 64;
    float s0, s1 = -3.0e38f;
    {
      bool masked = gz || (qm == 0.f) || (mk[j0] == 0.f);
      s0 = masked ? -10000.f
                  : ATT_SCALE * (st0 * Ts[j0][0] + st1 * Ts[j0][1] + st2 * Ts[j0][2] + hi + gs[j0] + wc);
    }
    if (j1 < NR) {
      bool masked = gz || (qm == 0.f) || (mk[j1] == 0.f);
      s1 = masked ? -10000.f
                  : ATT_SCALE * (st0 * Ts[j1][0] + st1 * Ts[j1][1] + st2 * Ts[j1][2] + hi + gs[j1] + wc);
    }
    float mx = wave_max(fmaxf(s0, s1));
    float p0 = __expf(s0 - mx);
    float p1 = (j1 < NR) ? __expf(s1 - mx) : 0.f;
    float ssum = wave_sum(p0 + p1);
    float y0 = wave_sum(p0 * Ts[j0][0] + ((j1 < NR) ? p1 * Ts[j1][0] : 0.f));
    float y1 = wave_sum(p0 * Ts[j0][1] + ((j1 < NR) ? p1 * Ts[j1][1] : 0.f));
    float y2 = wave_sum(p0 * Ts[j0][2] + ((j1 < NR) ? p1 * Ts[j1][2] : 0.f));
    if (lane == 0) {
      size_t oidx = (MODE == 0) ? (((size_t)b * NM + p) * NVx + i) * O
                                : (((size_t)b * NVx + p) * NM + i) * O;
      float inv = 1.f / ssum;
      Yout[oidx] = y0 * inv;
      Yout[oidx + 1] = y1 * inv;
      if (O == 3) Yout[oidx + 2] = y2 * inv;
    }
  }
}

// WHICH 0: key[b,m,d] += max_n Y2[b,n,m,:]·V2[:,d] + dv[d]
// WHICH 1: val[b,n,d] += max_m Y2[b,n,m,:]·V2[:,d] + dv[d]
template <int WHICH>
__global__ __launch_bounds__(256) void k_maxupd(
    const float* __restrict__ Y2, const float* __restrict__ F,
    float* __restrict__ dst, int NVx, int O)
{
  __shared__ float Ys[NNV][3];
  const int blk = blockIdx.x;
  int b, p, NR;
  if (WHICH == 0) { b = blk >> 6; p = blk & 63; NR = NVx; }
  else            { b = blk / NVx; p = blk - b * NVx; NR = NM; }
  const int tid = threadIdx.x;
  for (int j = tid; j < NR; j += 256) {
    size_t idx = (WHICH == 0) ? (((size_t)b * NVx + j) * NM + p) * O
                              : (((size_t)b * NVx + p) * NM + j) * O;
    Ys[j][0] = Y2[idx];
    Ys[j][1] = Y2[idx + 1];
    Ys[j][2] = (O == 3) ? Y2[idx + 2] : 0.f;
  }
  __syncthreads();
  const float* V2 = F + OF_V2;
  const float* dv = F + OF_dv;
  for (int d = tid; d < ND; d += 256) {
    float v0 = V2[d], v1 = V2[ND + d], v2 = (O == 3) ? V2[2 * ND + d] : 0.f;
    float mx = -3.0e38f;
    for (int j = 0; j < NR; ++j)
      mx = fmaxf(mx, Ys[j][0] * v0 + Ys[j][1] * v1 + Ys[j][2] * v2);
    size_t di = (WHICH == 0) ? (((size_t)b * NM + p) * ND + d)
                             : (((size_t)b * NVx + p) * ND + d);
    dst[di] += mx + dv[d];
  }
}

// argmax over 3 class logits at nv=0 -> km2
__global__ void k_type(const float* __restrict__ tl, const float* __restrict__ key_mask,
                       float* __restrict__ km2)
{
  int i = blockIdx.x * blockDim.x + threadIdx.x;
  if (i >= NB * NM) return;
  const float* p = tl + (size_t)i * NNV * 3;
  float l0 = p[0], l1 = p[1], l2 = p[2];
  int arg = 0;
  float best = l0;
  if (l1 > best) { best = l1; arg = 1; }
  if (l2 > best) { best = l2; arg = 2; }
  km2[i] = (key_mask[i] != 0.f && arg == 1) ? 1.f : 0.f;
}

__global__ void k_multi(const float* __restrict__ a, const float* __restrict__ bb,
                        const float* __restrict__ bc, float* __restrict__ out)
{
  int i = blockIdx.x * blockDim.x + threadIdx.x;
  if (i >= NB * NM * NM * 2) return;
  int c = i & 1;
  int t = i >> 1;
  int n = t % NM; t /= NM;
  int m = t % NM;
  int b = t / NM;
  out[i] = a[((size_t)b * NM + m) * 2 + c] + bb[((size_t)b * NM + n) * 2 + c] + bc[c];
}

static void run_rounds(hipStream_t stream,
                       float* keyb, float* valb,
                       const float* kmp, const float* vmp, int vmOff, int vmStride,
                       const float* Wb, const float* lwp, const float* lbp,
                       const float* fwp, const float* fbp,
                       const float* qwp, const float* qbp,
                       int O, int NVx,
                       float* tmp, float* L, float* Y1, float* Y2,
                       float* linK, float* linV, float* fold, float* outp)
{
  dim3 blk(256);
  k_fold1<<<dim3(6), blk, 0, stream>>>(fwp, fbp, qwp, qbp, fold, O);
  k_fold2<<<dim3(6), blk, 0, stream>>>(qwp, qbp, fold, O);
  k_fold3<<<dim3(1), dim3(64), 0, stream>>>(fold, O);
  const int nT = (NVx + 63) / 64;
  for (int r = 0; r < 5; ++r) {
    k_sproj<<<dim3((NB * NM * O + 255) / 256), blk, 0, stream>>>(keyb, lwp, linK, NB * NM, O, 2 * ND, 0);
    k_sproj<<<dim3((NB * NVx * O + 255) / 256), blk, 0, stream>>>(valb, lwp, linV, NB * NVx, O, 2 * ND, ND);
    k_tmp<<<dim3(8, 1, NB * O), blk, 0, stream>>>(keyb, Wb, tmp, O);
    if (r < 4) {
      k_bil<0><<<dim3(nT, 1, NB * O), blk, 0, stream>>>(tmp, valb, linK, linV, lbp, kmp, vmp, vmOff, vmStride, L, NVx, O);
      k_att<0><<<dim3(NB * NM), blk, 0, stream>>>(L, Y1, fold, kmp, vmp, vmOff, vmStride, NVx, O);
      k_att<1><<<dim3(NB * NVx), blk, 0, stream>>>(Y1, Y2, fold, kmp, vmp, vmOff, vmStride, NVx, O);
      k_maxupd<0><<<dim3(NB * NM), blk, 0, stream>>>(Y2, fold, keyb, NVx, O);
      k_maxupd<1><<<dim3(NB * NVx), blk, 0, stream>>>(Y2, fold, valb, NVx, O);
    } else {
      k_bil<1><<<dim3(nT, 1, NB * O), blk, 0, stream>>>(tmp, valb, linK, linV, lbp, kmp, vmp, vmOff, vmStride, outp, NVx, O);
    }
  }
}

extern "C" void kernel_launch(void* const* d_in, const int* in_sizes, int n_in,
                              void* d_out, int out_size, void* d_ws, size_t ws_size,
                              hipStream_t stream)
{
  const float* key        = (const float*)d_in[0];
  const float* value      = (const float*)d_in[1];
  const float* key_mask   = (const float*)d_in[2];
  const float* value_mask = (const float*)d_in[3];
  const float* w_kt = (const float*)d_in[4];  const float* b_kt = (const float*)d_in[5];
  const float* w_vt = (const float*)d_in[6];  const float* b_vt = (const float*)d_in[7];
  const float* w_km = (const float*)d_in[8];  const float* b_km = (const float*)d_in[9];
  const float* w_vm = (const float*)d_in[10]; const float* b_vm = (const float*)d_in[11];
  const float* w_ks = (const float*)d_in[12]; const float* b_ks = (const float*)d_in[13];
  const float* w_vs = (const float*)d_in[14]; const float* b_vs = (const float*)d_in[15];
  const float* bt_W = (const float*)d_in[16]; const float* bt_lw = (const float*)d_in[17];
  const float* bt_lb = (const float*)d_in[18];
  const float* bi_W = (const float*)d_in[19]; const float* bi_lw = (const float*)d_in[20];
  const float* bi_lb = (const float*)d_in[21];
  const float* w_ffnt = (const float*)d_in[22]; const float* b_ffnt = (const float*)d_in[23];
  const float* w_ffn  = (const float*)d_in[24]; const float* b_ffn  = (const float*)d_in[25];
  const float* qkvt_w = (const float*)d_in[26]; const float* qkvt_b = (const float*)d_in[27];
  const float* qkv_w  = (const float*)d_in[28]; const float* qkv_b  = (const float*)d_in[29];
  const float* w_cls  = (const float*)d_in[30]; const float* b_cls  = (const float*)d_in[31];

  float* ws = (float*)d_ws;
  size_t off = 0;
  float* kt   = ws + off; off += (size_t)NB * NM * ND;       // 983040
  float* vt   = ws + off; off += (size_t)NB * NNV * ND;      // 998400
  float* tmp  = ws + off; off += (size_t)NB * 3 * NM * ND;   // 2949120
  float* L    = ws + off; off += (size_t)NB * NM * NNV * 3;  // 399360
  float* Y1   = ws + off; off += (size_t)NB * NM * NNV * 3;
  float* Y2   = ws + off; off += (size_t)NB * NM * NNV * 3;
  float* linK = ws + off; off += (size_t)NB * NM * 3;
  float* linV = ws + off; off += (size_t)NB * NNV * 3;
  float* fold = ws + off; off += FOLD_SZ;
  float* km2  = ws + off; off += (size_t)NB * NM;
  float* a2   = ws + off; off += (size_t)NB * NM * 2;
  float* b2   = ws + off; off += (size_t)NB * NM * 2;
  (void)off; (void)ws_size; (void)in_sizes; (void)n_in; (void)out_size;

  float* out_type   = (float*)d_out;                               // B*M*NV*3
  float* out_multi  = out_type + (size_t)NB * NM * NNV * 3;        // B*M*64*2
  float* out_single = out_multi + (size_t)NB * NM * NM * 2;        // B*M*64*2

  dim3 blk(256);

  // type path inputs
  k_proj<<<dim3(8, 32), blk, 0, stream>>>(key, w_kt, b_kt, kt, NB * NM, ND, NH, NM, 0, NM * NH);
  k_proj<<<dim3(8, 33), blk, 0, stream>>>(value, w_vt, b_vt, vt, NB * NNV, ND, NH, NNV, 0, NNV * NH);
  run_rounds(stream, kt, vt, key_mask, value_mask, 0, NNV,
             bt_W, bt_lw, bt_lb, w_ffnt, b_ffnt, qkvt_w, qkvt_b, 3, NNV,
             tmp, L, Y1, Y2, linK, linV, fold, out_type);

  // type decision -> km2
  k_type<<<dim3(8), blk, 0, stream>>>(out_type, key_mask, km2);

  // multi logits (km_f / vm_f live in tmp, which is free between the two paths)
  float* kmf = tmp;
  float* vmf = tmp + (size_t)NB * NM * ND;
  k_proj<<<dim3(8, 32), blk, 0, stream>>>(key, w_km, b_km, kmf, NB * NM, ND, NH, NM, 0, NM * NH);
  k_proj<<<dim3(8, 32), blk, 0, stream>>>(value, w_vm, b_vm, vmf, NB * NM, ND, NH, NM, 1, NNV * NH);
  k_sproj<<<dim3((NB * NM * 2 + 255) / 256), blk, 0, stream>>>(kmf, w_cls, a2, NB * NM, 2, 2 * ND, 0);
  k_sproj<<<dim3((NB * NM * 2 + 255) / 256), blk, 0, stream>>>(vmf, w_cls, b2, NB * NM, 2, 2 * ND, ND);
  k_multi<<<dim3((NB * NM * NM * 2 + 255) / 256), blk, 0, stream>>>(a2, b2, b_cls, out_multi);

  // single path (reuse kt/vt buffers)
  k_proj<<<dim3(8, 32), blk, 0, stream>>>(key, w_ks, b_ks, kt, NB * NM, ND, NH, NM, 0, NM * NH);
  k_proj<<<dim3(8, 32), blk, 0, stream>>>(value, w_vs, b_vs, vt, NB * NM, ND, NH, NM, 1, NNV * NH);
  run_rounds(stream, kt, vt, km2, value_mask, 1, NNV,
             bi_W, bi_lw, bi_lb, w_ffn, b_ffn, qkv_w, qkv_b, 2, NM,
             tmp, L, Y1, Y2, linK, linV, fold, out_single);
}

// Round 2
// 2158.770 us; speedup vs baseline: 2.2121x; 2.2121x over previous
//
#include <hip/hip_runtime.h>
#include <math.h>

// ---------------- problem constants ----------------
constexpr int NB = 32;    // B
constexpr int NM = 64;    // M
constexpr int NNV = 65;   // NV
constexpr int NH = 960;   // H
constexpr int ND = 480;   // D
constexpr float ATT_SCALE = 0.045643546458763842f;  // D^-0.5

// fold-buffer offsets (floats). P blocks always strided for O=3.
constexpr int OF_Pq = 0;              // 3 parts x (3*480)
constexpr int OF_cq = 4320;           // 3 parts x 480
constexpr int OF_Q2 = 5760;           // 3 parts x (3*480)
constexpr int OF_V2 = OF_Q2 + 2*1440; // 8640
constexpr int OF_dq = 10080;          // 3 parts x 480
constexpr int OF_dv = OF_dq + 2*480;  // 11040
constexpr int OF_S  = 11520;          // 9  (S2 at +16)
constexpr int OF_u  = 11529;          // 3
constexpr int OF_r  = 11532;          // 3
constexpr int OF_w  = 11535;          // 1
constexpr int FOLD_SZ = 11552;

__device__ __forceinline__ float wave_max(float v) {
#pragma unroll
  for (int d = 32; d; d >>= 1) v = fmaxf(v, __shfl_xor(v, d));
  return v;
}
__device__ __forceinline__ float wave_sum(float v) {
#pragma unroll
  for (int d = 32; d; d >>= 1) v += __shfl_xor(v, d);
  return v;
}

// ---------------- batched projection GEMM ----------------
// C[r,n] = sum_h X[b*xbs + (x0+rr)*K + h] * W[n,h] + bias[n],  r = b*rpb+rr, n<480
struct ProjCfg {
  const float* X; const float* W; const float* bias; float* C;
  int R; int x0; int rpb; int xbs;
};

__global__ __launch_bounds__(256) void k_proj4(
    ProjCfg c0, ProjCfg c1, ProjCfg c2, ProjCfg c3, int K)
{
  const int z = blockIdx.z;
  ProjCfg cfg = (z == 0) ? c0 : (z == 1) ? c1 : (z == 2) ? c2 : c3;
  const int m0 = blockIdx.y * 64;
  if (m0 >= cfg.R) return;
  const int n0 = blockIdx.x * 64;
  __shared__ __align__(16) float As[16][68];
  __shared__ __align__(16) float Bs[16][68];
  const int tid = threadIdx.x;
  const int tm = tid >> 4, tn = tid & 15;
  const int lm = tid >> 2, lk4 = (tid & 3) * 4;
  const float* Arow = nullptr;
  {
    int r = m0 + lm;
    if (r < cfg.R) {
      int b = r / cfg.rpb, rr = r - b * cfg.rpb;
      Arow = cfg.X + (size_t)b * cfg.xbs + (size_t)(cfg.x0 + rr) * K;
    }
  }
  const float* Brow = nullptr;
  {
    int n = n0 + lm;
    if (n < ND) Brow = cfg.W + (size_t)n * K;
  }
  float acc[4][4] = {};
  for (int k0 = 0; k0 < K; k0 += 16) {
    float4 av = Arow ? *(const float4*)(Arow + k0 + lk4) : make_float4(0.f, 0.f, 0.f, 0.f);
    float4 bv = Brow ? *(const float4*)(Brow + k0 + lk4) : make_float4(0.f, 0.f, 0.f, 0.f);
    As[lk4 + 0][lm] = av.x; As[lk4 + 1][lm] = av.y;
    As[lk4 + 2][lm] = av.z; As[lk4 + 3][lm] = av.w;
    Bs[lk4 + 0][lm] = bv.x; Bs[lk4 + 1][lm] = bv.y;
    Bs[lk4 + 2][lm] = bv.z; Bs[lk4 + 3][lm] = bv.w;
    __syncthreads();
#pragma unroll
    for (int kk = 0; kk < 16; ++kk) {
      float4 a = *(const float4*)&As[kk][tm * 4];
      float4 b = *(const float4*)&Bs[kk][tn * 4];
      acc[0][0] += a.x * b.x; acc[0][1] += a.x * b.y; acc[0][2] += a.x * b.z; acc[0][3] += a.x * b.w;
      acc[1][0] += a.y * b.x; acc[1][1] += a.y * b.y; acc[1][2] += a.y * b.z; acc[1][3] += a.y * b.w;
      acc[2][0] += a.z * b.x; acc[2][1] += a.z * b.y; acc[2][2] += a.z * b.z; acc[2][3] += a.z * b.w;
      acc[3][0] += a.w * b.x; acc[3][1] += a.w * b.y; acc[3][2] += a.w * b.z; acc[3][3] += a.w * b.w;
    }
    __syncthreads();
  }
#pragma unroll
  for (int i = 0; i < 4; ++i) {
    int r = m0 + tm * 4 + i;
    if (r >= cfg.R) continue;
#pragma unroll
    for (int j = 0; j < 4; ++j) {
      int n = n0 + tn * 4 + j;
      if (n < ND) cfg.C[(size_t)r * ND + n] = acc[i][j] + cfg.bias[n];
    }
  }
}

// tmp[z=b*O+o][m,d2] = sum_d1 Key[b][m,d1] * W[o][d1,d2]   (NN gemm, M=64, K=N=480)
__global__ __launch_bounds__(256) void k_tmp(
    const float* __restrict__ Key, const float* __restrict__ W,
    float* __restrict__ T, int O)
{
  const int z = blockIdx.z;
  const int b = z / O, o = z - b * O;
  const float* A = Key + (size_t)b * NM * ND;
  const float* Bm = W + (size_t)o * ND * ND;
  float* C = T + (size_t)z * NM * ND;
  __shared__ __align__(16) float As[16][68];
  __shared__ __align__(16) float Bs[16][68];
  const int tid = threadIdx.x;
  const int tm = tid >> 4, tn = tid & 15;
  const int n0 = blockIdx.x * 64;
  const int lm = tid >> 2, lk4 = (tid & 3) * 4;       // A loader
  const int bkk = tid >> 4, bn4 = (tid & 15) * 4;     // B loader
  const float* Arow = A + (size_t)lm * ND;
  const bool bok = (n0 + bn4) < ND;
  float acc[4][4] = {};
  for (int k0 = 0; k0 < ND; k0 += 16) {
    float4 av = *(const float4*)(Arow + k0 + lk4);
    float4 bv = bok ? *(const float4*)(Bm + (size_t)(k0 + bkk) * ND + n0 + bn4)
                    : make_float4(0.f, 0.f, 0.f, 0.f);
    As[lk4 + 0][lm] = av.x; As[lk4 + 1][lm] = av.y;
    As[lk4 + 2][lm] = av.z; As[lk4 + 3][lm] = av.w;
    *(float4*)&Bs[bkk][bn4] = bv;
    __syncthreads();
#pragma unroll
    for (int kk = 0; kk < 16; ++kk) {
      float4 a = *(const float4*)&As[kk][tm * 4];
      float4 b = *(const float4*)&Bs[kk][tn * 4];
      acc[0][0] += a.x * b.x; acc[0][1] += a.x * b.y; acc[0][2] += a.x * b.z; acc[0][3] += a.x * b.w;
      acc[1][0] += a.y * b.x; acc[1][1] += a.y * b.y; acc[1][2] += a.y * b.z; acc[1][3] += a.y * b.w;
      acc[2][0] += a.z * b.x; acc[2][1] += a.z * b.y; acc[2][2] += a.z * b.z; acc[2][3] += a.z * b.w;
      acc[3][0] += a.w * b.x; acc[3][1] += a.w * b.y; acc[3][2] += a.w * b.z; acc[3][3] += a.w * b.w;
    }
    __syncthreads();
  }
#pragma unroll
  for (int i = 0; i < 4; ++i) {
    int m = tm * 4 + i;
#pragma unroll
    for (int j = 0; j < 4; ++j) {
      int n = n0 + tn * 4 + j;
      if (n < ND) C[(size_t)m * ND + n] = acc[i][j];
    }
  }
}

// per-(b,m) bilinear: Out[b,m,n,o] = tmp[b,o][m,:]·Val[b][n,:] + linK + linV + lb[o]
template <int FINAL, int O>
__global__ __launch_bounds__(256) void k_bil(
    const float* __restrict__ T, const float* __restrict__ Val,
    const float* __restrict__ linK, const float* __restrict__ linV,
    const float* __restrict__ lb, const float* __restrict__ km,
    const float* __restrict__ vm, int vmOff, int vmStride,
    float* __restrict__ Out, int NVx)
{
  __shared__ float ts[O][ND];
  const int b = blockIdx.x >> 6, m = blockIdx.x & 63;
  const int tid = threadIdx.x;
  for (int idx = tid; idx < O * ND; idx += 256) {
    int o = idx / ND, d = idx - o * ND;
    ts[o][d] = T[(((size_t)b * O + o) * NM + m) * ND + d];
  }
  __syncthreads();
  const int wv = tid >> 6, lane = tid & 63;
  const float kmv = km[b * NM + m];
  for (int n = wv; n < NVx; n += 4) {
    const float* vrow = Val + ((size_t)b * NVx + n) * ND;
    float s0 = 0.f, s1 = 0.f, s2 = 0.f;
    for (int d = lane; d < ND; d += 64) {
      float v = vrow[d];
      s0 += v * ts[0][d];
      s1 += v * ts[1][d];
      if (O == 3) s2 += v * ts[2][d];
    }
    s0 = wave_sum(s0); s1 = wave_sum(s1);
    if (O == 3) s2 = wave_sum(s2);
    if (lane == 0) {
      float msk = FINAL ? kmv * vm[b * vmStride + vmOff + n] : 1.f;
      size_t ob = (((size_t)b * NM + m) * NVx + n) * O;
      size_t lkb = ((size_t)b * NM + m) * O;
      size_t lvb = ((size_t)b * NVx + n) * O;
      float r0 = s0 + linK[lkb + 0] + linV[lvb + 0] + lb[0];
      float r1 = s1 + linK[lkb + 1] + linV[lvb + 1] + lb[1];
      Out[ob + 0] = FINAL ? r0 * msk : r0;
      Out[ob + 1] = FINAL ? r1 * msk : r1;
      if (O == 3) {
        float r2 = s2 + linK[lkb + 2] + linV[lvb + 2] + lb[2];
        Out[ob + 2] = FINAL ? r2 * msk : r2;
      }
    }
  }
}

// Out[r,o] = X[r,:]·W[o, wOff:wOff+480]  (wave per output)
__global__ __launch_bounds__(256) void k_sproj(
    const float* __restrict__ X, const float* __restrict__ W,
    float* __restrict__ Out, int R, int O, int wStride, int wOff)
{
  int gid = blockIdx.x * 4 + (threadIdx.x >> 6);
  int lane = threadIdx.x & 63;
  if (gid >= R * O) return;
  int r = gid / O, o = gid - r * O;
  const float* x = X + (size_t)r * ND;
  const float* w = W + (size_t)o * wStride + wOff;
  float acc = 0.f;
  for (int d = lane; d < ND; d += 64) acc += x[d] * w[d];
  acc = wave_sum(acc);
  if (lane == 0) Out[gid] = acc;
}

// fold stage 1: P_q/P_k/P_v (OxD, zero-filled to 3) and c_q/c_k/c_v (D). wave per (part,c)
__global__ __launch_bounds__(256) void k_fold1(
    const float* __restrict__ fw, const float* __restrict__ fb,
    const float* __restrict__ qw, const float* __restrict__ qb,
    float* __restrict__ F, int O)
{
  int gid = blockIdx.x * 4 + (threadIdx.x >> 6);
  int lane = threadIdx.x & 63;
  if (gid >= 3 * ND) return;
  int part = gid / ND, c = gid - part * ND;
  const float* qrow = qw + (size_t)(part * ND + c) * ND;
  float p0 = 0.f, p1 = 0.f, p2 = 0.f, cc = 0.f;
  for (int d = lane; d < ND; d += 64) {
    float q = qrow[d];
    p0 += fw[d * O + 0] * q;
    p1 += fw[d * O + 1] * q;
    if (O == 3) p2 += fw[d * O + 2] * q;
    cc += fb[d] * q;
  }
  p0 = wave_sum(p0); p1 = wave_sum(p1); p2 = wave_sum(p2); cc = wave_sum(cc);
  if (lane == 0) {
    F[OF_Pq + part * 1440 + 0 * ND + c] = p0;
    F[OF_Pq + part * 1440 + 1 * ND + c] = p1;
    F[OF_Pq + part * 1440 + 2 * ND + c] = (O == 3) ? p2 : 0.f;
    F[OF_cq + part * ND + c] = cc + qb[part * ND + c];
  }
}

// fold stage 2: Q2/K2/V2 + d_q/d_k/d_v (waves 0..1439) and S/u/r/w (waves 1440..1455)
__global__ __launch_bounds__(256) void k_fold2(
    const float* __restrict__ qw, const float* __restrict__ qb,
    float* __restrict__ F, int O)
{
  int gid = blockIdx.x * 4 + (threadIdx.x >> 6);
  int lane = threadIdx.x & 63;
  if (gid < 3 * ND) {
    int part = gid / ND, c = gid - part * ND;
    const float* qrow = qw + (size_t)(part * ND + c) * ND;
    const float* Pv = F + OF_Pq + 2 * 1440;
    const float* cv = F + OF_cq + 2 * ND;
    float p0 = 0.f, p1 = 0.f, p2 = 0.f, cc = 0.f;
    for (int d = lane; d < ND; d += 64) {
      float q = qrow[d];
      p0 += Pv[0 * ND + d] * q;
      p1 += Pv[1 * ND + d] * q;
      if (O == 3) p2 += Pv[2 * ND + d] * q;
      cc += cv[d] * q;
    }
    p0 = wave_sum(p0); p1 = wave_sum(p1); p2 = wave_sum(p2); cc = wave_sum(cc);
    if (lane == 0) {
      F[OF_Q2 + part * 1440 + 0 * ND + c] = p0;
      F[OF_Q2 + part * 1440 + 1 * ND + c] = p1;
      F[OF_Q2 + part * 1440 + 2 * ND + c] = (O == 3) ? p2 : 0.f;
      F[OF_dq + part * ND + c] = cc + qb[part * ND + c];
    }
  } else if (gid < 3 * ND + 16) {
    int s = gid - 3 * ND;
    const float* Pq = F + OF_Pq;
    const float* Pk = F + OF_Pq + 1440;
    const float* cq = F + OF_cq;
    const float* ck = F + OF_cq + ND;
    float acc = 0.f;
    if (s < 9) {
      int o = s / 3, op = s % 3;
      bool ok = (o < O) && (op < O);
      if (ok) for (int c = lane; c < ND; c += 64) acc += Pq[o * ND + c] * Pk[op * ND + c];
      acc = wave_sum(acc);
      if (lane == 0) F[OF_S + s] = ok ? acc : 0.f;
    } else if (s < 12) {
      int o = s - 9; bool ok = o < O;
      if (ok) for (int c = lane; c < ND; c += 64) acc += Pq[o * ND + c] * ck[c];
      acc = wave_sum(acc);
      if (lane == 0) F[OF_u + o] = ok ? acc : 0.f;
    } else if (s < 15) {
      int o = s - 12; bool ok = o < O;
      if (ok) for (int c = lane; c < ND; c += 64) acc += cq[c] * Pk[o * ND + c];
      acc = wave_sum(acc);
      if (lane == 0) F[OF_r + o] = ok ? acc : 0.f;
    } else {
      for (int c = lane; c < ND; c += 64) acc += cq[c] * ck[c];
      acc = wave_sum(acc);
      if (lane == 0) F[OF_w] = acc;
    }
  }
}

// fold stage 3: S2/u2/r2/w2 (at +16). 16 waves.
__global__ __launch_bounds__(256) void k_fold3(float* __restrict__ F, int O)
{
  int s = blockIdx.x * 4 + (threadIdx.x >> 6);
  int lane = threadIdx.x & 63;
  if (s >= 16) return;
  const float* Q2 = F + OF_Q2;
  const float* K2 = F + OF_Q2 + 1440;
  const float* dq = F + OF_dq;
  const float* dk = F + OF_dq + ND;
  float acc = 0.f;
  if (s < 9) {
    int o = s / 3, op = s % 3;
    bool ok = (o < O) && (op < O);
    if (ok) for (int c = lane; c < ND; c += 64) acc += Q2[o * ND + c] * K2[op * ND + c];
    acc = wave_sum(acc);
    if (lane == 0) F[OF_S + 16 + s] = ok ? acc : 0.f;
  } else if (s < 12) {
    int o = s - 9; bool ok = o < O;
    if (ok) for (int c = lane; c < ND; c += 64) acc += Q2[o * ND + c] * dk[c];
    acc = wave_sum(acc);
    if (lane == 0) F[OF_u + 16 + o] = ok ? acc : 0.f;
  } else if (s < 15) {
    int o = s - 12; bool ok = o < O;
    if (ok) for (int c = lane; c < ND; c += 64) acc += dq[c] * K2[o * ND + c];
    acc = wave_sum(acc);
    if (lane == 0) F[OF_r + 16 + o] = ok ? acc : 0.f;
  } else {
    for (int c = lane; c < ND; c += 64) acc += dq[c] * dk[c];
    acc = wave_sum(acc);
    if (lane == 0) F[OF_w + 16] = acc;
  }
}

// MODE 0: att over NV axis per (b,m); MODE 1: att over M axis per (b,n)
template <int MODE>
__global__ __launch_bounds__(256) void k_att(
    const float* __restrict__ Tsrc, float* __restrict__ Yout,
    const float* __restrict__ F,
    const float* __restrict__ km, const float* __restrict__ vm,
    int vmOff, int vmStride, int NVx, int O)
{
  __shared__ float Ts[NNV][3], STs[NNV][3], hs[NNV], gs[NNV], mk[NNV];
  const int blk = blockIdx.x;
  int b, p, NR;
  if (MODE == 0) { b = blk >> 6; p = blk & 63; NR = NVx; }
  else           { b = blk / NVx; p = blk - b * NVx; NR = NM; }
  const int tid = threadIdx.x;
  const float gm = (MODE == 0) ? km[b * NM + p] : vm[b * vmStride + vmOff + p];
  for (int j = tid; j < NR; j += 256) {
    size_t idx = (MODE == 0) ? (((size_t)b * NM + p) * NVx + j) * O
                             : (((size_t)b * NM + j) * NVx + p) * O;
    Ts[j][0] = Tsrc[idx];
    Ts[j][1] = Tsrc[idx + 1];
    Ts[j][2] = (O == 3) ? Tsrc[idx + 2] : 0.f;
    mk[j] = (MODE == 0) ? vm[b * vmStride + vmOff + j] : km[b * NM + j];
  }
  __syncthreads();
  const float* Sm = F + OF_S + 16 * MODE;
  const float* uv = F + OF_u + 16 * MODE;
  const float* rv = F + OF_r + 16 * MODE;
  const float wc = F[OF_w + 16 * MODE];
  for (int j = tid; j < NR; j += 256) {
    float t0 = Ts[j][0], t1 = Ts[j][1], t2 = Ts[j][2];
    STs[j][0] = t0 * Sm[0] + t1 * Sm[3] + t2 * Sm[6];
    STs[j][1] = t0 * Sm[1] + t1 * Sm[4] + t2 * Sm[7];
    STs[j][2] = t0 * Sm[2] + t1 * Sm[5] + t2 * Sm[8];
    hs[j] = t0 * uv[0] + t1 * uv[1] + t2 * uv[2];
    gs[j] = t0 * rv[0] + t1 * rv[1] + t2 * rv[2];
  }
  __syncthreads();
  const int wv = tid >> 6, lane = tid & 63;
  const bool gz = (gm == 0.f);
  for (int i = wv; i < NR; i += 4) {
    const float qm = mk[i];
    const float st0 = STs[i][0], st1 = STs[i][1], st2 = STs[i][2], hi = hs[i];
    const int j0 = lane, j1 = lane + 64;
    float s0, s1 = -3.0e38f;
    {
      bool masked = gz || (qm == 0.f) || (mk[j0] == 0.f);
      s0 = masked ? -10000.f
                  : ATT_SCALE * (st0 * Ts[j0][0] + st1 * Ts[j0][1] + st2 * Ts[j0][2] + hi + gs[j0] + wc);
    }
    if (j1 < NR) {
      bool masked = gz || (qm == 0.f) || (mk[j1] == 0.f);
      s1 = masked ? -10000.f
                  : ATT_SCALE * (st0 * Ts[j1][0] + st1 * Ts[j1][1] + st2 * Ts[j1][2] + hi + gs[j1] + wc);
    }
    float mx = wave_max(fmaxf(s0, s1));
    float p0 = __expf(s0 - mx);
    float p1 = (j1 < NR) ? __expf(s1 - mx) : 0.f;
    float ssum = wave_sum(p0 + p1);
    float y0 = wave_sum(p0 * Ts[j0][0] + ((j1 < NR) ? p1 * Ts[j1][0] : 0.f));
    float y1 = wave_sum(p0 * Ts[j0][1] + ((j1 < NR) ? p1 * Ts[j1][1] : 0.f));
    float y2 = wave_sum(p0 * Ts[j0][2] + ((j1 < NR) ? p1 * Ts[j1][2] : 0.f));
    if (lane == 0) {
      size_t oidx = (MODE == 0) ? (((size_t)b * NM + p) * NVx + i) * O
                                : (((size_t)b * NVx + p) * NM + i) * O;
      float inv = 1.f / ssum;
      Yout[oidx] = y0 * inv;
      Yout[oidx + 1] = y1 * inv;
      if (O == 3) Yout[oidx + 2] = y2 * inv;
    }
  }
}

// WHICH 0: key[b,m,d] += max_n Y2[b,n,m,:]·V2[:,d] + dv[d]
// WHICH 1: val[b,n,d] += max_m Y2[b,n,m,:]·V2[:,d] + dv[d]
template <int WHICH>
__global__ __launch_bounds__(256) void k_maxupd(
    const float* __restrict__ Y2, const float* __restrict__ F,
    float* __restrict__ dst, int NVx, int O)
{
  __shared__ float Ys[NNV][3];
  const int blk = blockIdx.x;
  int b, p, NR;
  if (WHICH == 0) { b = blk >> 6; p = blk & 63; NR = NVx; }
  else            { b = blk / NVx; p = blk - b * NVx; NR = NM; }
  const int tid = threadIdx.x;
  for (int j = tid; j < NR; j += 256) {
    size_t idx = (WHICH == 0) ? (((size_t)b * NVx + j) * NM + p) * O
                              : (((size_t)b * NVx + p) * NM + j) * O;
    Ys[j][0] = Y2[idx];
    Ys[j][1] = Y2[idx + 1];
    Ys[j][2] = (O == 3) ? Y2[idx + 2] : 0.f;
  }
  __syncthreads();
  const float* V2 = F + OF_V2;
  const float* dv = F + OF_dv;
  for (int d = tid; d < ND; d += 256) {
    float v0 = V2[d], v1 = V2[ND + d], v2 = (O == 3) ? V2[2 * ND + d] : 0.f;
    float mx = -3.0e38f;
    for (int j = 0; j < NR; ++j)
      mx = fmaxf(mx, Ys[j][0] * v0 + Ys[j][1] * v1 + Ys[j][2] * v2);
    size_t di = (WHICH == 0) ? (((size_t)b * NM + p) * ND + d)
                             : (((size_t)b * NVx + p) * ND + d);
    dst[di] += mx + dv[d];
  }
}

// argmax over 3 class logits at nv=0 -> km2
__global__ void k_type(const float* __restrict__ tl, const float* __restrict__ key_mask,
                       float* __restrict__ km2)
{
  int i = blockIdx.x * blockDim.x + threadIdx.x;
  if (i >= NB * NM) return;
  const float* p = tl + (size_t)i * NNV * 3;
  float l0 = p[0], l1 = p[1], l2 = p[2];
  int arg = 0;
  float best = l0;
  if (l1 > best) { best = l1; arg = 1; }
  if (l2 > best) { best = l2; arg = 2; }
  km2[i] = (key_mask[i] != 0.f && arg == 1) ? 1.f : 0.f;
}

__global__ void k_multi(const float* __restrict__ a, const float* __restrict__ bb,
                        const float* __restrict__ bc, float* __restrict__ out)
{
  int i = blockIdx.x * blockDim.x + threadIdx.x;
  if (i >= NB * NM * NM * 2) return;
  int c = i & 1;
  int t = i >> 1;
  int n = t % NM; t /= NM;
  int m = t % NM;
  int b = t / NM;
  out[i] = a[((size_t)b * NM + m) * 2 + c] + bb[((size_t)b * NM + n) * 2 + c] + bc[c];
}

template <int O>
static void run_rounds(hipStream_t stream,
                       float* keyb, float* valb,
                       const float* kmp, const float* vmp, int vmOff, int vmStride,
                       const float* Wb, const float* lwp, const float* lbp,
                       const float* fwp, const float* fbp,
                       const float* qwp, const float* qbp,
                       int NVx,
                       float* tmp, float* L, float* Y1, float* Y2,
                       float* linK, float* linV, float* fold, float* outp)
{
  dim3 blk(256);
  k_fold1<<<dim3(360), blk, 0, stream>>>(fwp, fbp, qwp, qbp, fold, O);
  k_fold2<<<dim3(364), blk, 0, stream>>>(qwp, qbp, fold, O);
  k_fold3<<<dim3(4), blk, 0, stream>>>(fold, O);
  for (int r = 0; r < 5; ++r) {
    k_sproj<<<dim3((NB * NM * O + 3) / 4), blk, 0, stream>>>(keyb, lwp, linK, NB * NM, O, 2 * ND, 0);
    k_sproj<<<dim3((NB * NVx * O + 3) / 4), blk, 0, stream>>>(valb, lwp, linV, NB * NVx, O, 2 * ND, ND);
    k_tmp<<<dim3(8, 1, NB * O), blk, 0, stream>>>(keyb, Wb, tmp, O);
    if (r < 4) {
      k_bil<0, O><<<dim3(NB * NM), blk, 0, stream>>>(tmp, valb, linK, linV, lbp, kmp, vmp, vmOff, vmStride, L, NVx);
      k_att<0><<<dim3(NB * NM), blk, 0, stream>>>(L, Y1, fold, kmp, vmp, vmOff, vmStride, NVx, O);
      k_att<1><<<dim3(NB * NVx), blk, 0, stream>>>(Y1, Y2, fold, kmp, vmp, vmOff, vmStride, NVx, O);
      k_maxupd<0><<<dim3(NB * NM), blk, 0, stream>>>(Y2, fold, keyb, NVx, O);
      k_maxupd<1><<<dim3(NB * NVx), blk, 0, stream>>>(Y2, fold, valb, NVx, O);
    } else {
      k_bil<1, O><<<dim3(NB * NM), blk, 0, stream>>>(tmp, valb, linK, linV, lbp, kmp, vmp, vmOff, vmStride, outp, NVx);
    }
  }
}

extern "C" void kernel_launch(void* const* d_in, const int* in_sizes, int n_in,
                              void* d_out, int out_size, void* d_ws, size_t ws_size,
                              hipStream_t stream)
{
  const float* key        = (const float*)d_in[0];
  const float* value      = (const float*)d_in[1];
  const float* key_mask   = (const float*)d_in[2];
  const float* value_mask = (const float*)d_in[3];
  const float* w_kt = (const float*)d_in[4];  const float* b_kt = (const float*)d_in[5];
  const float* w_vt = (const float*)d_in[6];  const float* b_vt = (const float*)d_in[7];
  const float* w_km = (const float*)d_in[8];  const float* b_km = (const float*)d_in[9];
  const float* w_vm = (const float*)d_in[10]; const float* b_vm = (const float*)d_in[11];
  const float* w_ks = (const float*)d_in[12]; const float* b_ks = (const float*)d_in[13];
  const float* w_vs = (const float*)d_in[14]; const float* b_vs = (const float*)d_in[15];
  const float* bt_W = (const float*)d_in[16]; const float* bt_lw = (const float*)d_in[17];
  const float* bt_lb = (const float*)d_in[18];
  const float* bi_W = (const float*)d_in[19]; const float* bi_lw = (const float*)d_in[20];
  const float* bi_lb = (const float*)d_in[21];
  const float* w_ffnt = (const float*)d_in[22]; const float* b_ffnt = (const float*)d_in[23];
  const float* w_ffn  = (const float*)d_in[24]; const float* b_ffn  = (const float*)d_in[25];
  const float* qkvt_w = (const float*)d_in[26]; const float* qkvt_b = (const float*)d_in[27];
  const float* qkv_w  = (const float*)d_in[28]; const float* qkv_b  = (const float*)d_in[29];
  const float* w_cls  = (const float*)d_in[30]; const float* b_cls  = (const float*)d_in[31];

  float* ws = (float*)d_ws;
  size_t off = 0;
  float* kt   = ws + off; off += (size_t)NB * NM * ND;       // 983040
  float* vt   = ws + off; off += (size_t)NB * NNV * ND;      // 998400
  float* tmp  = ws + off; off += (size_t)NB * 3 * NM * ND;   // 2949120
  float* L    = ws + off; off += (size_t)NB * NM * NNV * 3;  // 399360
  float* Y1   = ws + off; off += (size_t)NB * NM * NNV * 3;
  float* Y2   = ws + off; off += (size_t)NB * NM * NNV * 3;
  float* linK = ws + off; off += (size_t)NB * NM * 3;
  float* linV = ws + off; off += (size_t)NB * NNV * 3;
  float* fold = ws + off; off += FOLD_SZ;
  float* km2  = ws + off; off += (size_t)NB * NM;
  float* a2   = ws + off; off += (size_t)NB * NM * 2;
  float* b2   = ws + off; off += (size_t)NB * NM * 2;
  (void)off; (void)ws_size; (void)in_sizes; (void)n_in; (void)out_size;

  float* out_type   = (float*)d_out;                               // B*M*NV*3
  float* out_multi  = out_type + (size_t)NB * NM * NNV * 3;        // B*M*64*2
  float* out_single = out_multi + (size_t)NB * NM * NM * 2;        // B*M*64*2

  dim3 blk(256);

  // ---- type-path projections (batched: key->kt, value->vt) ----
  ProjCfg pkt = { key,   w_kt, b_kt, kt, NB * NM,  0, NM,  NM * NH };
  ProjCfg pvt = { value, w_vt, b_vt, vt, NB * NNV, 0, NNV, NNV * NH };
  ProjCfg pnone = { key, w_kt, b_kt, kt, 0, 0, NM, NM * NH };
  k_proj4<<<dim3(8, 33, 2), blk, 0, stream>>>(pkt, pvt, pnone, pnone, NH);

  run_rounds<3>(stream, kt, vt, key_mask, value_mask, 0, NNV,
                bt_W, bt_lw, bt_lb, w_ffnt, b_ffnt, qkvt_w, qkvt_b, NNV,
                tmp, L, Y1, Y2, linK, linV, fold, out_type);

  // type decision -> km2
  k_type<<<dim3(8), blk, 0, stream>>>(out_type, key_mask, km2);

  // ---- remaining 4 projections in one batched launch ----
  // kt <- key@w_ks (single path), vt <- v1@w_vs, tmp[0] <- key@w_km, tmp[1M] <- v1@w_vm
  float* kmf = tmp;
  float* vmf = tmp + (size_t)NB * NM * ND;
  ProjCfg pks = { key,   w_ks, b_ks, kt,  NB * NM, 0, NM, NM * NH };
  ProjCfg pvs = { value, w_vs, b_vs, vt,  NB * NM, 1, NM, NNV * NH };
  ProjCfg pkm = { key,   w_km, b_km, kmf, NB * NM, 0, NM, NM * NH };
  ProjCfg pvm = { value, w_vm, b_vm, vmf, NB * NM, 1, NM, NNV * NH };
  k_proj4<<<dim3(8, 32, 4), blk, 0, stream>>>(pks, pvs, pkm, pvm, NH);

  // multi logits
  k_sproj<<<dim3((NB * NM * 2 + 3) / 4), blk, 0, stream>>>(kmf, w_cls, a2, NB * NM, 2, 2 * ND, 0);
  k_sproj<<<dim3((NB * NM * 2 + 3) / 4), blk, 0, stream>>>(vmf, w_cls, b2, NB * NM, 2, 2 * ND, ND);
  k_multi<<<dim3((NB * NM * NM * 2 + 255) / 256), blk, 0, stream>>>(a2, b2, b_cls, out_multi);

  // single path (kt/vt now hold ks_f / vs_f; tmp is free again for rounds)
  run_rounds<2>(stream, kt, vt, km2, value_mask, 1, NNV,
                bi_W, bi_lw, bi_lb, w_ffn, b_ffn, qkv_w, qkv_b, NM,
                tmp, L, Y1, Y2, linK, linV, fold, out_single);
}

// Round 3
// 1901.512 us; speedup vs baseline: 2.5113x; 1.1353x over previous
//
#include <hip/hip_runtime.h>
#include <math.h>

// ---------------- problem constants ----------------
constexpr int NB = 32;    // B
constexpr int NM = 64;    // M
constexpr int NNV = 65;   // NV
constexpr int NH = 960;   // H
constexpr int ND = 480;   // D
constexpr float ATT_SCALE = 0.045643546458763842f;  // D^-0.5

// fold-buffer offsets (floats). P blocks always strided for O=3.
constexpr int OF_Pq = 0;              // 3 parts x (3*480)
constexpr int OF_cq = 4320;           // 3 parts x 480
constexpr int OF_Q2 = 5760;           // 3 parts x (3*480)
constexpr int OF_V2 = OF_Q2 + 2*1440; // 8640
constexpr int OF_dq = 10080;          // 3 parts x 480
constexpr int OF_dv = OF_dq + 2*480;  // 11040
constexpr int OF_S  = 11520;          // 9  (S2 at +16)
constexpr int OF_u  = 11529;          // 3
constexpr int OF_r  = 11532;          // 3
constexpr int OF_w  = 11535;          // 1
constexpr int FOLD_SZ = 11552;

__device__ __forceinline__ float wave_sum(float v) {
#pragma unroll
  for (int d = 32; d; d >>= 1) v += __shfl_xor(v, d);
  return v;
}

// ---------------- batched projection GEMM (XCD-chunk swizzled 1D grid) ----------------
// C[r,n] = sum_h X[b*xbs + (x0+rr)*K + h] * W[n,h] + bias[n],  r = b*rpb+rr, n<480
struct ProjCfg {
  const float* X; const float* W; const float* bias; float* C;
  int R; int x0; int rpb; int xbs;
};

__global__ __launch_bounds__(256) void k_proj4(
    ProjCfg c0, ProjCfg c1, ProjCfg c2, ProjCfg c3, int K, int My)
{
  // chunked XCD swizzle: physical dispatch p -> logical block l such that
  // XCD k (= p%8 round-robin) processes a contiguous logical range.
  int p = blockIdx.x;
  int total = gridDim.x;
  int q = total >> 3, r = total & 7;
  int xk = p & 7, idx = p >> 3;
  int l = (xk < r) ? xk * (q + 1) + idx : r * (q + 1) + (xk - r) * q + idx;
  int z = l / (8 * My);
  int rem = l - z * (8 * My);
  int my = rem >> 3, nx = rem & 7;

  ProjCfg cfg = (z == 0) ? c0 : (z == 1) ? c1 : (z == 2) ? c2 : c3;
  const int m0 = my * 64;
  if (m0 >= cfg.R) return;
  const int n0 = nx * 64;
  __shared__ __align__(16) float As[16][68];
  __shared__ __align__(16) float Bs[16][68];
  const int tid = threadIdx.x;
  const int tm = tid >> 4, tn = tid & 15;
  const int lm = tid >> 2, lk4 = (tid & 3) * 4;
  const float* Arow = nullptr;
  {
    int rr0 = m0 + lm;
    if (rr0 < cfg.R) {
      int b = rr0 / cfg.rpb, rr = rr0 - b * cfg.rpb;
      Arow = cfg.X + (size_t)b * cfg.xbs + (size_t)(cfg.x0 + rr) * K;
    }
  }
  const float* Brow = nullptr;
  {
    int n = n0 + lm;
    if (n < ND) Brow = cfg.W + (size_t)n * K;
  }
  float acc[4][4] = {};
  for (int k0 = 0; k0 < K; k0 += 16) {
    float4 av = Arow ? *(const float4*)(Arow + k0 + lk4) : make_float4(0.f, 0.f, 0.f, 0.f);
    float4 bv = Brow ? *(const float4*)(Brow + k0 + lk4) : make_float4(0.f, 0.f, 0.f, 0.f);
    As[lk4 + 0][lm] = av.x; As[lk4 + 1][lm] = av.y;
    As[lk4 + 2][lm] = av.z; As[lk4 + 3][lm] = av.w;
    Bs[lk4 + 0][lm] = bv.x; Bs[lk4 + 1][lm] = bv.y;
    Bs[lk4 + 2][lm] = bv.z; Bs[lk4 + 3][lm] = bv.w;
    __syncthreads();
#pragma unroll
    for (int kk = 0; kk < 16; ++kk) {
      float4 a = *(const float4*)&As[kk][tm * 4];
      float4 b = *(const float4*)&Bs[kk][tn * 4];
      acc[0][0] += a.x * b.x; acc[0][1] += a.x * b.y; acc[0][2] += a.x * b.z; acc[0][3] += a.x * b.w;
      acc[1][0] += a.y * b.x; acc[1][1] += a.y * b.y; acc[1][2] += a.y * b.z; acc[1][3] += a.y * b.w;
      acc[2][0] += a.z * b.x; acc[2][1] += a.z * b.y; acc[2][2] += a.z * b.z; acc[2][3] += a.z * b.w;
      acc[3][0] += a.w * b.x; acc[3][1] += a.w * b.y; acc[3][2] += a.w * b.z; acc[3][3] += a.w * b.w;
    }
    __syncthreads();
  }
#pragma unroll
  for (int i = 0; i < 4; ++i) {
    int rr = m0 + tm * 4 + i;
    if (rr >= cfg.R) continue;
#pragma unroll
    for (int j = 0; j < 4; ++j) {
      int n = n0 + tn * 4 + j;
      if (n < ND) cfg.C[(size_t)rr * ND + n] = acc[i][j] + cfg.bias[n];
    }
  }
}

// tmp[z=b*O+o][m,d2] = sum_d1 Key[b][m,d1] * W[o][d1,d2]
// grid (15, NB): n-tile 32 (480 = 15*32 exact), all O per block. 256 threads.
template <int O>
__global__ __launch_bounds__(256) void k_tmp(
    const float* __restrict__ Key, const float* __restrict__ W,
    float* __restrict__ T)
{
  const int b = blockIdx.y;
  const int n0 = blockIdx.x * 32;
  const float* A = Key + (size_t)b * NM * ND;
  __shared__ __align__(16) float As[16][68];
  __shared__ __align__(16) float Bs[O][16][36];
  const int tid = threadIdx.x;
  const int tm = tid >> 4, tn = tid & 15;
  const int lm = tid >> 2, lk4 = (tid & 3) * 4;  // A loader
  const int bk = (tid & 127) >> 3, bn4 = (tid & 7) * 4;  // B loader (tid<128)
  float acc[O][4][2] = {};
  for (int k0 = 0; k0 < ND; k0 += 16) {
    float4 av = *(const float4*)(A + (size_t)lm * ND + k0 + lk4);
    As[lk4 + 0][lm] = av.x; As[lk4 + 1][lm] = av.y;
    As[lk4 + 2][lm] = av.z; As[lk4 + 3][lm] = av.w;
    if (tid < 128) {
#pragma unroll
      for (int o = 0; o < O; ++o) {
        float4 bv = *(const float4*)(W + (size_t)o * ND * ND + (size_t)(k0 + bk) * ND + n0 + bn4);
        *(float4*)&Bs[o][bk][bn4] = bv;
      }
    }
    __syncthreads();
#pragma unroll
    for (int kk = 0; kk < 16; ++kk) {
      float4 a = *(const float4*)&As[kk][tm * 4];
#pragma unroll
      for (int o = 0; o < O; ++o) {
        float2 bv = *(const float2*)&Bs[o][kk][tn * 2];
        acc[o][0][0] += a.x * bv.x; acc[o][0][1] += a.x * bv.y;
        acc[o][1][0] += a.y * bv.x; acc[o][1][1] += a.y * bv.y;
        acc[o][2][0] += a.z * bv.x; acc[o][2][1] += a.z * bv.y;
        acc[o][3][0] += a.w * bv.x; acc[o][3][1] += a.w * bv.y;
      }
    }
    __syncthreads();
  }
#pragma unroll
  for (int o = 0; o < O; ++o) {
    float* C = T + ((size_t)(b * O + o) * NM) * ND;
#pragma unroll
    for (int i = 0; i < 4; ++i)
#pragma unroll
      for (int j = 0; j < 2; ++j)
        C[(size_t)(tm * 4 + i) * ND + n0 + tn * 2 + j] = acc[o][i][j];
  }
}

// fused bilinear + attention(MODE0) per (b,m): L row -> softmax over NV -> Y1 row
template <int O, int NVX>
__global__ __launch_bounds__(256) void k_bilatt0(
    const float* __restrict__ T, const float* __restrict__ Val,
    const float* __restrict__ linK, const float* __restrict__ linV,
    const float* __restrict__ lb, const float* __restrict__ F,
    const float* __restrict__ km, const float* __restrict__ vm,
    int vmOff, int vmStride, float* __restrict__ Y1)
{
  __shared__ float ts[O][ND];
  __shared__ float Vs[NVX][97];
  __shared__ float Ls[NVX][3];
  __shared__ float STs[NVX][3];
  __shared__ float hs[NVX], gs[NVX], mkj[NVX];
  const int b = blockIdx.x >> 6, m = blockIdx.x & 63;
  const int tid = threadIdx.x;
  for (int idx = tid; idx < O * ND; idx += 256) {
    int o = idx / ND, d = idx - o * ND;
    ts[o][d] = T[(((size_t)b * O + o) * NM + m) * ND + d];
  }
  for (int j = tid; j < NVX; j += 256) mkj[j] = vm[b * vmStride + vmOff + j];
  const float gm = km[b * NM + m];
  const bool gz = (gm == 0.f);

  // bilinear: acc[n,o] = ts[o]·Val[n]
  const int t = tid;
  const int an = (t < NVX * O) ? (t % NVX) : 0;
  const int ao = (t < NVX * O) ? (t / NVX) : 0;
  float acc = 0.f;
  for (int c = 0; c < 5; ++c) {
    const int d0 = c * 96;
    __syncthreads();
    for (int u = tid; u < NVX * 24; u += 256) {
      int n = u / 24, f = (u - n * 24) * 4;
      float4 v = *(const float4*)(Val + ((size_t)b * NVX + n) * ND + d0 + f);
      Vs[n][f + 0] = v.x; Vs[n][f + 1] = v.y; Vs[n][f + 2] = v.z; Vs[n][f + 3] = v.w;
    }
    __syncthreads();
    if (t < NVX * O) {
#pragma unroll 8
      for (int dd = 0; dd < 96; ++dd) acc += Vs[an][dd] * ts[ao][d0 + dd];
    }
  }
  if (t < NVX * O) {
    Ls[an][ao] = acc + linK[((size_t)b * NM + m) * O + ao]
                     + linV[((size_t)b * NVX + an) * O + ao] + lb[ao];
  }
  __syncthreads();
  // per-j precompute
  const float* Sm = F + OF_S;
  const float u0 = F[OF_u], u1 = F[OF_u + 1], u2 = F[OF_u + 2];
  const float r0 = F[OF_r], r1 = F[OF_r + 1], r2 = F[OF_r + 2];
  const float wc = F[OF_w];
  if (tid < NVX) {
    int j = tid;
    float t0 = Ls[j][0], t1 = Ls[j][1], t2 = (O == 3) ? Ls[j][2] : 0.f;
    STs[j][0] = t0 * Sm[0] + t1 * Sm[3] + t2 * Sm[6];
    STs[j][1] = t0 * Sm[1] + t1 * Sm[4] + t2 * Sm[7];
    STs[j][2] = t0 * Sm[2] + t1 * Sm[5] + t2 * Sm[8];
    hs[j] = t0 * u0 + t1 * u1 + t2 * u2;
    gs[j] = t0 * r0 + t1 * r1 + t2 * r2;
  }
  __syncthreads();
  // thread-per-row softmax (two-pass)
  if (tid < NVX) {
    const int i = tid;
    const float qm = mkj[i];
    const float st0 = STs[i][0], st1 = STs[i][1], st2 = STs[i][2], hi = hs[i];
    const bool rowz = gz || (qm == 0.f);
    float mx = -3.0e38f;
    for (int j = 0; j < NVX; ++j) {
      float t0 = Ls[j][0], t1 = Ls[j][1];
      float s = st0 * t0 + st1 * t1 + hi + gs[j] + wc;
      if (O == 3) s += st2 * Ls[j][2];
      s = (rowz || mkj[j] == 0.f) ? -10000.f : ATT_SCALE * s;
      mx = fmaxf(mx, s);
    }
    float sum = 0.f, y0 = 0.f, y1 = 0.f, y2 = 0.f;
    for (int j = 0; j < NVX; ++j) {
      float t0 = Ls[j][0], t1 = Ls[j][1], t2 = (O == 3) ? Ls[j][2] : 0.f;
      float s = st0 * t0 + st1 * t1 + hi + gs[j] + wc;
      if (O == 3) s += st2 * t2;
      s = (rowz || mkj[j] == 0.f) ? -10000.f : ATT_SCALE * s;
      float pp = __expf(s - mx);
      sum += pp; y0 += pp * t0; y1 += pp * t1; y2 += pp * t2;
    }
    float inv = 1.f / sum;
    size_t ob = (((size_t)b * NM + m) * NVX + i) * O;
    Y1[ob + 0] = y0 * inv;
    Y1[ob + 1] = y1 * inv;
    if (O == 3) Y1[ob + 2] = y2 * inv;
  }
}

// fused attention(MODE1) + value-update + linV per (b,n)
template <int O, int NVX>
__global__ __launch_bounds__(256) void k_att1vupd(
    const float* __restrict__ Y1, float* __restrict__ Y2,
    const float* __restrict__ F,
    const float* __restrict__ km, const float* __restrict__ vm,
    int vmOff, int vmStride,
    float* __restrict__ valb, const float* __restrict__ lw,
    float* __restrict__ linV)
{
  __shared__ float Ys1[NM][3];
  __shared__ float STs[NM][3];
  __shared__ float hs[NM], gs[NM], mkm[NM];
  __shared__ float Ys2[NM][3];
  __shared__ float vrow[ND];
  const int b = blockIdx.x / NVX, n = blockIdx.x - b * NVX;
  const int tid = threadIdx.x;
  for (int u = tid; u < NM * O; u += 256) {
    int mm = u % NM, o = u / NM;
    Ys1[mm][o] = Y1[(((size_t)b * NM + mm) * NVX + n) * O + o];
  }
  if (tid < NM) mkm[tid] = km[b * NM + tid];
  const float gm = vm[b * vmStride + vmOff + n];
  const bool gz = (gm == 0.f);
  __syncthreads();
  const float* Sm = F + OF_S + 16;
  const float u0 = F[OF_u + 16], u1 = F[OF_u + 17], u2 = F[OF_u + 18];
  const float r0 = F[OF_r + 16], r1 = F[OF_r + 17], r2 = F[OF_r + 18];
  const float wc = F[OF_w + 16];
  if (tid < NM) {
    int j = tid;
    float t0 = Ys1[j][0], t1 = Ys1[j][1], t2 = (O == 3) ? Ys1[j][2] : 0.f;
    STs[j][0] = t0 * Sm[0] + t1 * Sm[3] + t2 * Sm[6];
    STs[j][1] = t0 * Sm[1] + t1 * Sm[4] + t2 * Sm[7];
    STs[j][2] = t0 * Sm[2] + t1 * Sm[5] + t2 * Sm[8];
    hs[j] = t0 * u0 + t1 * u1 + t2 * u2;
    gs[j] = t0 * r0 + t1 * r1 + t2 * r2;
  }
  __syncthreads();
  if (tid < NM) {
    const int i = tid;
    const float qm = mkm[i];
    const float st0 = STs[i][0], st1 = STs[i][1], st2 = STs[i][2], hi = hs[i];
    const bool rowz = gz || (qm == 0.f);
    float mx = -3.0e38f;
    for (int j = 0; j < NM; ++j) {
      float s = st0 * Ys1[j][0] + st1 * Ys1[j][1] + hi + gs[j] + wc;
      if (O == 3) s += st2 * Ys1[j][2];
      s = (rowz || mkm[j] == 0.f) ? -10000.f : ATT_SCALE * s;
      mx = fmaxf(mx, s);
    }
    float sum = 0.f, y0 = 0.f, y1 = 0.f, y2 = 0.f;
    for (int j = 0; j < NM; ++j) {
      float t0 = Ys1[j][0], t1 = Ys1[j][1], t2 = (O == 3) ? Ys1[j][2] : 0.f;
      float s = st0 * t0 + st1 * t1 + hi + gs[j] + wc;
      if (O == 3) s += st2 * t2;
      s = (rowz || mkm[j] == 0.f) ? -10000.f : ATT_SCALE * s;
      float pp = __expf(s - mx);
      sum += pp; y0 += pp * t0; y1 += pp * t1; y2 += pp * t2;
    }
    float inv = 1.f / sum;
    y0 *= inv; y1 *= inv; y2 *= inv;
    size_t ob = (((size_t)b * NVX + n) * NM + i) * O;
    Y2[ob + 0] = y0; Y2[ob + 1] = y1;
    if (O == 3) Y2[ob + 2] = y2;
    Ys2[i][0] = y0; Ys2[i][1] = y1; Ys2[i][2] = y2;
  }
  __syncthreads();
  // value update: val[b,n,d] += max_m Ys2[m,:]·V2[:,d] + dv[d]
  const float* V2 = F + OF_V2;
  const float* dv = F + OF_dv;
  for (int d = tid; d < ND; d += 256) {
    float v0 = V2[d], v1 = V2[ND + d], v2 = (O == 3) ? V2[2 * ND + d] : 0.f;
    float mx = -3.0e38f;
    for (int j = 0; j < NM; ++j) {
      float s = Ys2[j][0] * v0 + Ys2[j][1] * v1;
      if (O == 3) s += Ys2[j][2] * v2;
      mx = fmaxf(mx, s);
    }
    size_t di = ((size_t)b * NVX + n) * ND + d;
    float nv = valb[di] + mx + dv[d];
    valb[di] = nv;
    vrow[d] = nv;
  }
  __syncthreads();
  // linV[b,n,o] = vrow · lw[o, ND: ]
  const int wv = tid >> 6, lane = tid & 63;
  if (wv < O) {
    float acc = 0.f;
    for (int d = lane; d < ND; d += 64) acc += vrow[d] * lw[(size_t)wv * 2 * ND + ND + d];
    acc = wave_sum(acc);
    if (lane == 0) linV[((size_t)b * NVX + n) * O + wv] = acc;
  }
}

// fused key-update + linK per (b,m)
template <int O, int NVX>
__global__ __launch_bounds__(256) void k_kupd(
    const float* __restrict__ Y2, const float* __restrict__ F,
    float* __restrict__ keyb, const float* __restrict__ lw,
    float* __restrict__ linK)
{
  __shared__ float Ys[NVX][3];
  __shared__ float krow[ND];
  const int b = blockIdx.x >> 6, m = blockIdx.x & 63;
  const int tid = threadIdx.x;
  for (int u = tid; u < NVX * O; u += 256) {
    int j = u % NVX, o = u / NVX;
    Ys[j][o] = Y2[(((size_t)b * NVX + j) * NM + m) * O + o];
  }
  __syncthreads();
  const float* V2 = F + OF_V2;
  const float* dv = F + OF_dv;
  for (int d = tid; d < ND; d += 256) {
    float v0 = V2[d], v1 = V2[ND + d], v2 = (O == 3) ? V2[2 * ND + d] : 0.f;
    float mx = -3.0e38f;
    for (int j = 0; j < NVX; ++j) {
      float s = Ys[j][0] * v0 + Ys[j][1] * v1;
      if (O == 3) s += Ys[j][2] * v2;
      mx = fmaxf(mx, s);
    }
    size_t di = ((size_t)b * NM + m) * ND + d;
    float nv = keyb[di] + mx + dv[d];
    keyb[di] = nv;
    krow[d] = nv;
  }
  __syncthreads();
  const int wv = tid >> 6, lane = tid & 63;
  if (wv < O) {
    float acc = 0.f;
    for (int d = lane; d < ND; d += 64) acc += krow[d] * lw[(size_t)wv * 2 * ND + d];
    acc = wave_sum(acc);
    if (lane == 0) linK[((size_t)b * NM + m) * O + wv] = acc;
  }
}

// final bilinear with mask (wave-per-n), Out[b,m,n,o]
template <int O>
__global__ __launch_bounds__(256) void k_bilfin(
    const float* __restrict__ T, const float* __restrict__ Val,
    const float* __restrict__ linK, const float* __restrict__ linV,
    const float* __restrict__ lb, const float* __restrict__ km,
    const float* __restrict__ vm, int vmOff, int vmStride,
    float* __restrict__ Out, int NVx)
{
  __shared__ float ts[O][ND];
  const int b = blockIdx.x >> 6, m = blockIdx.x & 63;
  const int tid = threadIdx.x;
  for (int idx = tid; idx < O * ND; idx += 256) {
    int o = idx / ND, d = idx - o * ND;
    ts[o][d] = T[(((size_t)b * O + o) * NM + m) * ND + d];
  }
  __syncthreads();
  const int wv = tid >> 6, lane = tid & 63;
  const float kmv = km[b * NM + m];
  for (int n = wv; n < NVx; n += 4) {
    const float* vrow = Val + ((size_t)b * NVx + n) * ND;
    float s0 = 0.f, s1 = 0.f, s2 = 0.f;
    for (int d = lane; d < ND; d += 64) {
      float v = vrow[d];
      s0 += v * ts[0][d];
      s1 += v * ts[1][d];
      if (O == 3) s2 += v * ts[2][d];
    }
    s0 = wave_sum(s0); s1 = wave_sum(s1);
    if (O == 3) s2 = wave_sum(s2);
    if (lane == 0) {
      float msk = kmv * vm[b * vmStride + vmOff + n];
      size_t ob = (((size_t)b * NM + m) * NVx + n) * O;
      size_t lkb = ((size_t)b * NM + m) * O;
      size_t lvb = ((size_t)b * NVx + n) * O;
      Out[ob + 0] = (s0 + linK[lkb + 0] + linV[lvb + 0] + lb[0]) * msk;
      Out[ob + 1] = (s1 + linK[lkb + 1] + linV[lvb + 1] + lb[1]) * msk;
      if (O == 3) Out[ob + 2] = (s2 + linK[lkb + 2] + linV[lvb + 2] + lb[2]) * msk;
    }
  }
}

// Out[r,o] = X[r,:]·W[o, wOff:wOff+480]  (wave per output)
__global__ __launch_bounds__(256) void k_sproj(
    const float* __restrict__ X, const float* __restrict__ W,
    float* __restrict__ Out, int R, int O, int wStride, int wOff)
{
  int gid = blockIdx.x * 4 + (threadIdx.x >> 6);
  int lane = threadIdx.x & 63;
  if (gid >= R * O) return;
  int r = gid / O, o = gid - r * O;
  const float* x = X + (size_t)r * ND;
  const float* w = W + (size_t)o * wStride + wOff;
  float acc = 0.f;
  for (int d = lane; d < ND; d += 64) acc += x[d] * w[d];
  acc = wave_sum(acc);
  if (lane == 0) Out[gid] = acc;
}

// fold stage 1
__global__ __launch_bounds__(256) void k_fold1(
    const float* __restrict__ fw, const float* __restrict__ fb,
    const float* __restrict__ qw, const float* __restrict__ qb,
    float* __restrict__ F, int O)
{
  int gid = blockIdx.x * 4 + (threadIdx.x >> 6);
  int lane = threadIdx.x & 63;
  if (gid >= 3 * ND) return;
  int part = gid / ND, c = gid - part * ND;
  const float* qrow = qw + (size_t)(part * ND + c) * ND;
  float p0 = 0.f, p1 = 0.f, p2 = 0.f, cc = 0.f;
  for (int d = lane; d < ND; d += 64) {
    float q = qrow[d];
    p0 += fw[d * O + 0] * q;
    p1 += fw[d * O + 1] * q;
    if (O == 3) p2 += fw[d * O + 2] * q;
    cc += fb[d] * q;
  }
  p0 = wave_sum(p0); p1 = wave_sum(p1); p2 = wave_sum(p2); cc = wave_sum(cc);
  if (lane == 0) {
    F[OF_Pq + part * 1440 + 0 * ND + c] = p0;
    F[OF_Pq + part * 1440 + 1 * ND + c] = p1;
    F[OF_Pq + part * 1440 + 2 * ND + c] = (O == 3) ? p2 : 0.f;
    F[OF_cq + part * ND + c] = cc + qb[part * ND + c];
  }
}

// fold stage 2
__global__ __launch_bounds__(256) void k_fold2(
    const float* __restrict__ qw, const float* __restrict__ qb,
    float* __restrict__ F, int O)
{
  int gid = blockIdx.x * 4 + (threadIdx.x >> 6);
  int lane = threadIdx.x & 63;
  if (gid < 3 * ND) {
    int part = gid / ND, c = gid - part * ND;
    const float* qrow = qw + (size_t)(part * ND + c) * ND;
    const float* Pv = F + OF_Pq + 2 * 1440;
    const float* cv = F + OF_cq + 2 * ND;
    float p0 = 0.f, p1 = 0.f, p2 = 0.f, cc = 0.f;
    for (int d = lane; d < ND; d += 64) {
      float q = qrow[d];
      p0 += Pv[0 * ND + d] * q;
      p1 += Pv[1 * ND + d] * q;
      if (O == 3) p2 += Pv[2 * ND + d] * q;
      cc += cv[d] * q;
    }
    p0 = wave_sum(p0); p1 = wave_sum(p1); p2 = wave_sum(p2); cc = wave_sum(cc);
    if (lane == 0) {
      F[OF_Q2 + part * 1440 + 0 * ND + c] = p0;
      F[OF_Q2 + part * 1440 + 1 * ND + c] = p1;
      F[OF_Q2 + part * 1440 + 2 * ND + c] = (O == 3) ? p2 : 0.f;
      F[OF_dq + part * ND + c] = cc + qb[part * ND + c];
    }
  } else if (gid < 3 * ND + 16) {
    int s = gid - 3 * ND;
    const float* Pq = F + OF_Pq;
    const float* Pk = F + OF_Pq + 1440;
    const float* cq = F + OF_cq;
    const float* ck = F + OF_cq + ND;
    float acc = 0.f;
    if (s < 9) {
      int o = s / 3, op = s % 3;
      bool ok = (o < O) && (op < O);
      if (ok) for (int c = lane; c < ND; c += 64) acc += Pq[o * ND + c] * Pk[op * ND + c];
      acc = wave_sum(acc);
      if (lane == 0) F[OF_S + s] = ok ? acc : 0.f;
    } else if (s < 12) {
      int o = s - 9; bool ok = o < O;
      if (ok) for (int c = lane; c < ND; c += 64) acc += Pq[o * ND + c] * ck[c];
      acc = wave_sum(acc);
      if (lane == 0) F[OF_u + o] = ok ? acc : 0.f;
    } else if (s < 15) {
      int o = s - 12; bool ok = o < O;
      if (ok) for (int c = lane; c < ND; c += 64) acc += cq[c] * Pk[o * ND + c];
      acc = wave_sum(acc);
      if (lane == 0) F[OF_r + o] = ok ? acc : 0.f;
    } else {
      for (int c = lane; c < ND; c += 64) acc += cq[c] * ck[c];
      acc = wave_sum(acc);
      if (lane == 0) F[OF_w] = acc;
    }
  }
}

// fold stage 3
__global__ __launch_bounds__(256) void k_fold3(float* __restrict__ F, int O)
{
  int s = blockIdx.x * 4 + (threadIdx.x >> 6);
  int lane = threadIdx.x & 63;
  if (s >= 16) return;
  const float* Q2 = F + OF_Q2;
  const float* K2 = F + OF_Q2 + 1440;
  const float* dq = F + OF_dq;
  const float* dk = F + OF_dq + ND;
  float acc = 0.f;
  if (s < 9) {
    int o = s / 3, op = s % 3;
    bool ok = (o < O) && (op < O);
    if (ok) for (int c = lane; c < ND; c += 64) acc += Q2[o * ND + c] * K2[op * ND + c];
    acc = wave_sum(acc);
    if (lane == 0) F[OF_S + 16 + s] = ok ? acc : 0.f;
  } else if (s < 12) {
    int o = s - 9; bool ok = o < O;
    if (ok) for (int c = lane; c < ND; c += 64) acc += Q2[o * ND + c] * dk[c];
    acc = wave_sum(acc);
    if (lane == 0) F[OF_u + 16 + o] = ok ? acc : 0.f;
  } else if (s < 15) {
    int o = s - 12; bool ok = o < O;
    if (ok) for (int c = lane; c < ND; c += 64) acc += dq[c] * K2[o * ND + c];
    acc = wave_sum(acc);
    if (lane == 0) F[OF_r + 16 + o] = ok ? acc : 0.f;
  } else {
    for (int c = lane; c < ND; c += 64) acc += dq[c] * dk[c];
    acc = wave_sum(acc);
    if (lane == 0) F[OF_w + 16] = acc;
  }
}

// argmax over 3 class logits at nv=0 -> km2
__global__ void k_type(const float* __restrict__ tl, const float* __restrict__ key_mask,
                       float* __restrict__ km2)
{
  int i = blockIdx.x * blockDim.x + threadIdx.x;
  if (i >= NB * NM) return;
  const float* p = tl + (size_t)i * NNV * 3;
  float l0 = p[0], l1 = p[1], l2 = p[2];
  int arg = 0;
  float best = l0;
  if (l1 > best) { best = l1; arg = 1; }
  if (l2 > best) { best = l2; arg = 2; }
  km2[i] = (key_mask[i] != 0.f && arg == 1) ? 1.f : 0.f;
}

__global__ void k_multi(const float* __restrict__ a, const float* __restrict__ bb,
                        const float* __restrict__ bc, float* __restrict__ out)
{
  int i = blockIdx.x * blockDim.x + threadIdx.x;
  if (i >= NB * NM * NM * 2) return;
  int c = i & 1;
  int t = i >> 1;
  int n = t % NM; t /= NM;
  int m = t % NM;
  int b = t / NM;
  out[i] = a[((size_t)b * NM + m) * 2 + c] + bb[((size_t)b * NM + n) * 2 + c] + bc[c];
}

template <int O, int NVX>
static void run_rounds(hipStream_t stream,
                       float* keyb, float* valb,
                       const float* kmp, const float* vmp, int vmOff, int vmStride,
                       const float* Wb, const float* lwp, const float* lbp,
                       const float* fwp, const float* fbp,
                       const float* qwp, const float* qbp,
                       float* tmp, float* Y1, float* Y2,
                       float* linK, float* linV, float* fold, float* outp)
{
  dim3 blk(256);
  k_fold1<<<dim3(360), blk, 0, stream>>>(fwp, fbp, qwp, qbp, fold, O);
  k_fold2<<<dim3(364), blk, 0, stream>>>(qwp, qbp, fold, O);
  k_fold3<<<dim3(4), blk, 0, stream>>>(fold, O);
  k_sproj<<<dim3((NB * NM * O + 3) / 4), blk, 0, stream>>>(keyb, lwp, linK, NB * NM, O, 2 * ND, 0);
  k_sproj<<<dim3((NB * NVX * O + 3) / 4), blk, 0, stream>>>(valb, lwp, linV, NB * NVX, O, 2 * ND, ND);
  for (int r = 0; r < 5; ++r) {
    k_tmp<O><<<dim3(15, NB), blk, 0, stream>>>(keyb, Wb, tmp);
    if (r < 4) {
      k_bilatt0<O, NVX><<<dim3(NB * NM), blk, 0, stream>>>(
          tmp, valb, linK, linV, lbp, fold, kmp, vmp, vmOff, vmStride, Y1);
      k_att1vupd<O, NVX><<<dim3(NB * NVX), blk, 0, stream>>>(
          Y1, Y2, fold, kmp, vmp, vmOff, vmStride, valb, lwp, linV);
      k_kupd<O, NVX><<<dim3(NB * NM), blk, 0, stream>>>(Y2, fold, keyb, lwp, linK);
    } else {
      k_bilfin<O><<<dim3(NB * NM), blk, 0, stream>>>(
          tmp, valb, linK, linV, lbp, kmp, vmp, vmOff, vmStride, outp, NVX);
    }
  }
}

extern "C" void kernel_launch(void* const* d_in, const int* in_sizes, int n_in,
                              void* d_out, int out_size, void* d_ws, size_t ws_size,
                              hipStream_t stream)
{
  const float* key        = (const float*)d_in[0];
  const float* value      = (const float*)d_in[1];
  const float* key_mask   = (const float*)d_in[2];
  const float* value_mask = (const float*)d_in[3];
  const float* w_kt = (const float*)d_in[4];  const float* b_kt = (const float*)d_in[5];
  const float* w_vt = (const float*)d_in[6];  const float* b_vt = (const float*)d_in[7];
  const float* w_km = (const float*)d_in[8];  const float* b_km = (const float*)d_in[9];
  const float* w_vm = (const float*)d_in[10]; const float* b_vm = (const float*)d_in[11];
  const float* w_ks = (const float*)d_in[12]; const float* b_ks = (const float*)d_in[13];
  const float* w_vs = (const float*)d_in[14]; const float* b_vs = (const float*)d_in[15];
  const float* bt_W = (const float*)d_in[16]; const float* bt_lw = (const float*)d_in[17];
  const float* bt_lb = (const float*)d_in[18];
  const float* bi_W = (const float*)d_in[19]; const float* bi_lw = (const float*)d_in[20];
  const float* bi_lb = (const float*)d_in[21];
  const float* w_ffnt = (const float*)d_in[22]; const float* b_ffnt = (const float*)d_in[23];
  const float* w_ffn  = (const float*)d_in[24]; const float* b_ffn  = (const float*)d_in[25];
  const float* qkvt_w = (const float*)d_in[26]; const float* qkvt_b = (const float*)d_in[27];
  const float* qkv_w  = (const float*)d_in[28]; const float* qkv_b  = (const float*)d_in[29];
  const float* w_cls  = (const float*)d_in[30]; const float* b_cls  = (const float*)d_in[31];

  float* ws = (float*)d_ws;
  size_t off = 0;
  float* kt   = ws + off; off += (size_t)NB * NM * ND;
  float* vt   = ws + off; off += (size_t)NB * NNV * ND;
  float* tmp  = ws + off; off += (size_t)NB * 3 * NM * ND;
  float* Y1   = ws + off; off += (size_t)NB * NM * NNV * 3;
  float* Y2   = ws + off; off += (size_t)NB * NM * NNV * 3;
  float* linK = ws + off; off += (size_t)NB * NM * 3;
  float* linV = ws + off; off += (size_t)NB * NNV * 3;
  float* fold = ws + off; off += FOLD_SZ;
  float* km2  = ws + off; off += (size_t)NB * NM;
  float* a2   = ws + off; off += (size_t)NB * NM * 2;
  float* b2   = ws + off; off += (size_t)NB * NM * 2;
  (void)off; (void)ws_size; (void)in_sizes; (void)n_in; (void)out_size;

  float* out_type   = (float*)d_out;                               // B*M*NV*3
  float* out_multi  = out_type + (size_t)NB * NM * NNV * 3;        // B*M*64*2
  float* out_single = out_multi + (size_t)NB * NM * NM * 2;        // B*M*64*2

  dim3 blk(256);

  // ---- type-path projections (batched, XCD-swizzled) ----
  ProjCfg pkt = { key,   w_kt, b_kt, kt, NB * NM,  0, NM,  NM * NH };
  ProjCfg pvt = { value, w_vt, b_vt, vt, NB * NNV, 0, NNV, NNV * NH };
  ProjCfg pnone = { key, w_kt, b_kt, kt, 0, 0, NM, NM * NH };
  k_proj4<<<dim3(8 * 33 * 2), blk, 0, stream>>>(pkt, pvt, pnone, pnone, NH, 33);

  run_rounds<3, NNV>(stream, kt, vt, key_mask, value_mask, 0, NNV,
                     bt_W, bt_lw, bt_lb, w_ffnt, b_ffnt, qkvt_w, qkvt_b,
                     tmp, Y1, Y2, linK, linV, fold, out_type);

  // type decision -> km2
  k_type<<<dim3(8), blk, 0, stream>>>(out_type, key_mask, km2);

  // ---- remaining 4 projections in one batched launch ----
  float* kmf = tmp;
  float* vmf = tmp + (size_t)NB * NM * ND;
  ProjCfg pks = { key,   w_ks, b_ks, kt,  NB * NM, 0, NM, NM * NH };
  ProjCfg pvs = { value, w_vs, b_vs, vt,  NB * NM, 1, NM, NNV * NH };
  ProjCfg pkm = { key,   w_km, b_km, kmf, NB * NM, 0, NM, NM * NH };
  ProjCfg pvm = { value, w_vm, b_vm, vmf, NB * NM, 1, NM, NNV * NH };
  k_proj4<<<dim3(8 * 32 * 4), blk, 0, stream>>>(pks, pvs, pkm, pvm, NH, 32);

  // multi logits
  k_sproj<<<dim3((NB * NM * 2 + 3) / 4), blk, 0, stream>>>(kmf, w_cls, a2, NB * NM, 2, 2 * ND, 0);
  k_sproj<<<dim3((NB * NM * 2 + 3) / 4), blk, 0, stream>>>(vmf, w_cls, b2, NB * NM, 2, 2 * ND, ND);
  k_multi<<<dim3((NB * NM * NM * 2 + 255) / 256), blk, 0, stream>>>(a2, b2, b_cls, out_multi);

  // single path (kt/vt now hold ks_f / vs_f; tmp free for rounds)
  run_rounds<2, NM>(stream, kt, vt, km2, value_mask, 1, NNV,
                    bi_W, bi_lw, bi_lb, w_ffn, b_ffn, qkv_w, qkv_b,
                    tmp, Y1, Y2, linK, linV, fold, out_single);
}

// Round 4
// 1479.514 us; speedup vs baseline: 3.2276x; 1.2852x over previous
//
#include <hip/hip_runtime.h>
#include <math.h>

// ---------------- problem constants ----------------
constexpr int NB = 32;    // B
constexpr int NM = 64;    // M
constexpr int NNV = 65;   // NV
constexpr int NH = 960;   // H
constexpr int ND = 480;   // D
constexpr float ATT_SCALE = 0.045643546458763842f;  // D^-0.5

// fold-buffer offsets (floats). P blocks always strided for O=3.
constexpr int OF_Pq = 0;              // 3 parts x (3*480)
constexpr int OF_cq = 4320;           // 3 parts x 480
constexpr int OF_Q2 = 5760;           // 3 parts x (3*480)
constexpr int OF_V2 = OF_Q2 + 2*1440; // 8640
constexpr int OF_dq = 10080;          // 3 parts x 480
constexpr int OF_dv = OF_dq + 2*480;  // 11040
constexpr int OF_S  = 11520;          // 9  (S2 at +16)
constexpr int OF_u  = 11529;          // 3
constexpr int OF_r  = 11532;          // 3
constexpr int OF_w  = 11535;          // 1
constexpr int FOLD_SZ = 11552;

__device__ __forceinline__ float wave_sum(float v) {
#pragma unroll
  for (int d = 32; d; d >>= 1) v += __shfl_xor(v, d);
  return v;
}

// ---------------- one merged projection GEMM (6 configs, XCD-chunk swizzled) ----------------
struct ProjCfg {
  const float* X; const float* W; const float* bias; float* C;
  int R; int x0; int rpb; int xbs;
};
struct Proj6 { ProjCfg c[6]; };

// panel layout (64-row m-panels): c0:32, c1:33, c2:32, c3:32, c4:32, c5:32 -> 193 panels x 8 n-tiles
__global__ __launch_bounds__(256) void k_proj6(Proj6 P, int K)
{
  int p = blockIdx.x;           // 1544 = 193*8, divisible by 8
  int q = gridDim.x >> 3;
  int xk = p & 7, idx = p >> 3;
  int l = xk * q + idx;         // contiguous logical range per XCD
  int mp = l >> 3, nx = l & 7;
  ProjCfg cfg; int my;
  if      (mp < 32)  { cfg = P.c[0]; my = mp; }
  else if (mp < 65)  { cfg = P.c[1]; my = mp - 32; }
  else if (mp < 97)  { cfg = P.c[2]; my = mp - 65; }
  else if (mp < 129) { cfg = P.c[3]; my = mp - 97; }
  else if (mp < 161) { cfg = P.c[4]; my = mp - 129; }
  else               { cfg = P.c[5]; my = mp - 161; }
  const int m0 = my * 64;
  if (m0 >= cfg.R) return;
  const int n0 = nx * 64;
  __shared__ __align__(16) float As[16][68];
  __shared__ __align__(16) float Bs[16][68];
  const int tid = threadIdx.x;
  const int tm = tid >> 4, tn = tid & 15;
  const int lm = tid >> 2, lk4 = (tid & 3) * 4;
  const float* Arow = nullptr;
  {
    int rr0 = m0 + lm;
    if (rr0 < cfg.R) {
      int b = rr0 / cfg.rpb, rr = rr0 - b * cfg.rpb;
      Arow = cfg.X + (size_t)b * cfg.xbs + (size_t)(cfg.x0 + rr) * K;
    }
  }
  const float* Brow = nullptr;
  {
    int n = n0 + lm;
    if (n < ND) Brow = cfg.W + (size_t)n * K;
  }
  float acc[4][4] = {};
  for (int k0 = 0; k0 < K; k0 += 16) {
    float4 av = Arow ? *(const float4*)(Arow + k0 + lk4) : make_float4(0.f, 0.f, 0.f, 0.f);
    float4 bv = Brow ? *(const float4*)(Brow + k0 + lk4) : make_float4(0.f, 0.f, 0.f, 0.f);
    As[lk4 + 0][lm] = av.x; As[lk4 + 1][lm] = av.y;
    As[lk4 + 2][lm] = av.z; As[lk4 + 3][lm] = av.w;
    Bs[lk4 + 0][lm] = bv.x; Bs[lk4 + 1][lm] = bv.y;
    Bs[lk4 + 2][lm] = bv.z; Bs[lk4 + 3][lm] = bv.w;
    __syncthreads();
#pragma unroll
    for (int kk = 0; kk < 16; ++kk) {
      float4 a = *(const float4*)&As[kk][tm * 4];
      float4 b = *(const float4*)&Bs[kk][tn * 4];
      acc[0][0] += a.x * b.x; acc[0][1] += a.x * b.y; acc[0][2] += a.x * b.z; acc[0][3] += a.x * b.w;
      acc[1][0] += a.y * b.x; acc[1][1] += a.y * b.y; acc[1][2] += a.y * b.z; acc[1][3] += a.y * b.w;
      acc[2][0] += a.z * b.x; acc[2][1] += a.z * b.y; acc[2][2] += a.z * b.z; acc[2][3] += a.z * b.w;
      acc[3][0] += a.w * b.x; acc[3][1] += a.w * b.y; acc[3][2] += a.w * b.z; acc[3][3] += a.w * b.w;
    }
    __syncthreads();
  }
#pragma unroll
  for (int i = 0; i < 4; ++i) {
    int rr = m0 + tm * 4 + i;
    if (rr >= cfg.R) continue;
#pragma unroll
    for (int j = 0; j < 4; ++j) {
      int n = n0 + tn * 4 + j;
      if (n < ND) cfg.C[(size_t)rr * ND + n] = acc[i][j] + cfg.bias[n];
    }
  }
}

// tmp[z=b*O+o][m,d2] = sum_d1 Key[b][m,d1] * W[o][d1,d2]
template <int O>
__global__ __launch_bounds__(256) void k_tmp(
    const float* __restrict__ Key, const float* __restrict__ W,
    float* __restrict__ T)
{
  const int b = blockIdx.y;
  const int n0 = blockIdx.x * 32;
  const float* A = Key + (size_t)b * NM * ND;
  __shared__ __align__(16) float As[16][68];
  __shared__ __align__(16) float Bs[O][16][36];
  const int tid = threadIdx.x;
  const int tm = tid >> 4, tn = tid & 15;
  const int lm = tid >> 2, lk4 = (tid & 3) * 4;
  const int bk = (tid & 127) >> 3, bn4 = (tid & 7) * 4;
  float acc[O][4][2] = {};
  for (int k0 = 0; k0 < ND; k0 += 16) {
    float4 av = *(const float4*)(A + (size_t)lm * ND + k0 + lk4);
    As[lk4 + 0][lm] = av.x; As[lk4 + 1][lm] = av.y;
    As[lk4 + 2][lm] = av.z; As[lk4 + 3][lm] = av.w;
    if (tid < 128) {
#pragma unroll
      for (int o = 0; o < O; ++o) {
        float4 bv = *(const float4*)(W + (size_t)o * ND * ND + (size_t)(k0 + bk) * ND + n0 + bn4);
        *(float4*)&Bs[o][bk][bn4] = bv;
      }
    }
    __syncthreads();
#pragma unroll
    for (int kk = 0; kk < 16; ++kk) {
      float4 a = *(const float4*)&As[kk][tm * 4];
#pragma unroll
      for (int o = 0; o < O; ++o) {
        float2 bv = *(const float2*)&Bs[o][kk][tn * 2];
        acc[o][0][0] += a.x * bv.x; acc[o][0][1] += a.x * bv.y;
        acc[o][1][0] += a.y * bv.x; acc[o][1][1] += a.y * bv.y;
        acc[o][2][0] += a.z * bv.x; acc[o][2][1] += a.z * bv.y;
        acc[o][3][0] += a.w * bv.x; acc[o][3][1] += a.w * bv.y;
      }
    }
    __syncthreads();
  }
#pragma unroll
  for (int o = 0; o < O; ++o) {
    float* C = T + ((size_t)(b * O + o) * NM) * ND;
#pragma unroll
    for (int i = 0; i < 4; ++i)
#pragma unroll
      for (int j = 0; j < 2; ++j)
        C[(size_t)(tm * 4 + i) * ND + n0 + tn * 2 + j] = acc[o][i][j];
  }
}

// fused bilinear + attention(MODE0) per (b,m) with parallel softmax
template <int O, int NVX>
__global__ __launch_bounds__(256) void k_bilatt0(
    const float* __restrict__ T, const float* __restrict__ Val,
    const float* __restrict__ linK, const float* __restrict__ linV,
    const float* __restrict__ lb, const float* __restrict__ F,
    const float* __restrict__ km, const float* __restrict__ vm,
    int vmOff, int vmStride, float* __restrict__ Y1)
{
  __shared__ float Ls[NVX][3];
  __shared__ float STs[NVX][3];
  __shared__ float hs[NVX], gs[NVX], mkj[NVX];
  __shared__ float Pm[NVX][66];
  __shared__ float rmx[NVX][3];
  __shared__ float rsum[NVX][3];
  __shared__ float ry[NVX][3][3];
  __shared__ float lvs[NVX][3];
  const int b = blockIdx.x >> 6, m = blockIdx.x & 63;
  const int tid = threadIdx.x;
  const int lane = tid & 63, w = tid >> 6;

  for (int j = tid; j < NVX; j += 256) {
    mkj[j] = vm[b * vmStride + vmOff + j];
#pragma unroll
    for (int o = 0; o < O; ++o) lvs[j][o] = linV[((size_t)b * NVX + j) * O + o];
  }
  float4 tsr[O][2];
#pragma unroll
  for (int o = 0; o < O; ++o) {
    const float4* trow = (const float4*)(T + (((size_t)b * O + o) * NM + m) * (size_t)ND);
    tsr[o][0] = trow[lane];
    tsr[o][1] = (lane < 56) ? trow[64 + lane] : make_float4(0.f, 0.f, 0.f, 0.f);
  }
  float lk[O];
#pragma unroll
  for (int o = 0; o < O; ++o) lk[o] = linK[((size_t)b * NM + m) * O + o] + lb[o];
  const float gm = km[b * NM + m];
  const bool gz = (gm == 0.f);

  // phase 1: L-row via global Val (L2) + register ts
  for (int n = w; n < NVX; n += 4) {
    const float4* vrow = (const float4*)(Val + ((size_t)b * NVX + n) * (size_t)ND);
    float4 v0 = vrow[lane];
    float4 v1 = (lane < 56) ? vrow[64 + lane] : make_float4(0.f, 0.f, 0.f, 0.f);
    float a[3] = {0.f, 0.f, 0.f};
#pragma unroll
    for (int o = 0; o < O; ++o) {
      a[o] = v0.x * tsr[o][0].x + v0.y * tsr[o][0].y + v0.z * tsr[o][0].z + v0.w * tsr[o][0].w
           + v1.x * tsr[o][1].x + v1.y * tsr[o][1].y + v1.z * tsr[o][1].z + v1.w * tsr[o][1].w;
    }
#pragma unroll
    for (int o = 0; o < O; ++o) a[o] = wave_sum(a[o]);
    if (lane == 0) {
#pragma unroll
      for (int o = 0; o < O; ++o) Ls[n][o] = a[o] + lk[o] + lvs[n][o];
      if (O == 2) Ls[n][2] = 0.f;
    }
  }
  __syncthreads();
  const float* Sm = F + OF_S;
  const float u0 = F[OF_u], u1 = F[OF_u + 1], u2 = F[OF_u + 2];
  const float r0 = F[OF_r], r1 = F[OF_r + 1], r2 = F[OF_r + 2];
  const float wc = F[OF_w];
  if (tid < NVX) {
    int j = tid;
    float t0 = Ls[j][0], t1 = Ls[j][1], t2 = Ls[j][2];
    STs[j][0] = t0 * Sm[0] + t1 * Sm[3] + t2 * Sm[6];
    STs[j][1] = t0 * Sm[1] + t1 * Sm[4] + t2 * Sm[7];
    STs[j][2] = t0 * Sm[2] + t1 * Sm[5] + t2 * Sm[8];
    hs[j] = t0 * u0 + t1 * u1 + t2 * u2;
    gs[j] = t0 * r0 + t1 * r1 + t2 * r2;
  }
  __syncthreads();
  // phase 2: parallel softmax, 3 j-strips per row
  const bool act = tid < NVX * 3;
  int i = 0, qq = 0, jlo = 0, jhi = 0;
  float st0 = 0, st1 = 0, st2 = 0, hi = 0;
  bool rowz = true;
  if (act) {
    i = tid / 3; qq = tid - i * 3;
    jlo = qq * 22; jhi = (jlo + 22 < NVX) ? jlo + 22 : NVX;
    st0 = STs[i][0]; st1 = STs[i][1]; st2 = STs[i][2]; hi = hs[i];
    rowz = gz || (mkj[i] == 0.f);
    float mx = -3.0e38f;
    for (int j = jlo; j < jhi; ++j) {
      float s = st0 * Ls[j][0] + st1 * Ls[j][1] + hi + gs[j] + wc;
      if (O == 3) s += st2 * Ls[j][2];
      s = (rowz || mkj[j] == 0.f) ? -10000.f : ATT_SCALE * s;
      Pm[i][j] = s;
      mx = fmaxf(mx, s);
    }
    rmx[i][qq] = mx;
  }
  __syncthreads();
  if (act) {
    float mx = fmaxf(fmaxf(rmx[i][0], rmx[i][1]), rmx[i][2]);
    float sum = 0.f, y0 = 0.f, y1 = 0.f, y2 = 0.f;
    for (int j = jlo; j < jhi; ++j) {
      float pp = __expf(Pm[i][j] - mx);
      sum += pp; y0 += pp * Ls[j][0]; y1 += pp * Ls[j][1];
      if (O == 3) y2 += pp * Ls[j][2];
    }
    rsum[i][qq] = sum; ry[i][qq][0] = y0; ry[i][qq][1] = y1; ry[i][qq][2] = y2;
  }
  __syncthreads();
  if (tid < NVX) {
    int ii = tid;
    float sum = rsum[ii][0] + rsum[ii][1] + rsum[ii][2];
    float y0 = ry[ii][0][0] + ry[ii][1][0] + ry[ii][2][0];
    float y1 = ry[ii][0][1] + ry[ii][1][1] + ry[ii][2][1];
    float y2 = ry[ii][0][2] + ry[ii][1][2] + ry[ii][2][2];
    float inv = 1.f / sum;
    size_t ob = (((size_t)b * NM + m) * NVX + ii) * O;
    Y1[ob + 0] = y0 * inv;
    Y1[ob + 1] = y1 * inv;
    if (O == 3) Y1[ob + 2] = y2 * inv;
  }
}

// fused attention(MODE1) + value-update + linV per (b,n), parallel softmax
template <int O, int NVX>
__global__ __launch_bounds__(256) void k_att1vupd(
    const float* __restrict__ Y1, float* __restrict__ Y2,
    const float* __restrict__ F,
    const float* __restrict__ km, const float* __restrict__ vm,
    int vmOff, int vmStride,
    float* __restrict__ valb, const float* __restrict__ lw,
    float* __restrict__ linV)
{
  __shared__ float Ys1[NM][3];
  __shared__ float STs[NM][3];
  __shared__ float hs[NM], gs[NM], mkm[NM];
  __shared__ float Pm[NM][66];
  __shared__ float rmx[NM][3];
  __shared__ float rsum[NM][3];
  __shared__ float ry[NM][3][3];
  __shared__ float Ys2[NM][3];
  __shared__ float vrow[ND];
  const int b = blockIdx.x / NVX, n = blockIdx.x - b * NVX;
  const int tid = threadIdx.x;
  for (int u = tid; u < NM * O; u += 256) {
    int mm = u % NM, o = u / NM;
    Ys1[mm][o] = Y1[(((size_t)b * NM + mm) * NVX + n) * O + o];
  }
  if (tid < NM) {
    mkm[tid] = km[b * NM + tid];
    if (O == 2) Ys1[tid][2] = 0.f;
  }
  const float gm = vm[b * vmStride + vmOff + n];
  const bool gz = (gm == 0.f);
  __syncthreads();
  const float* Sm = F + OF_S + 16;
  const float u0 = F[OF_u + 16], u1 = F[OF_u + 17], u2 = F[OF_u + 18];
  const float r0 = F[OF_r + 16], r1 = F[OF_r + 17], r2 = F[OF_r + 18];
  const float wc = F[OF_w + 16];
  if (tid < NM) {
    int j = tid;
    float t0 = Ys1[j][0], t1 = Ys1[j][1], t2 = Ys1[j][2];
    STs[j][0] = t0 * Sm[0] + t1 * Sm[3] + t2 * Sm[6];
    STs[j][1] = t0 * Sm[1] + t1 * Sm[4] + t2 * Sm[7];
    STs[j][2] = t0 * Sm[2] + t1 * Sm[5] + t2 * Sm[8];
    hs[j] = t0 * u0 + t1 * u1 + t2 * u2;
    gs[j] = t0 * r0 + t1 * r1 + t2 * r2;
  }
  __syncthreads();
  const bool act = tid < NM * 3;
  int i = 0, qq = 0, jlo = 0, jhi = 0;
  float st0 = 0, st1 = 0, st2 = 0, hi = 0;
  bool rowz = true;
  if (act) {
    i = tid / 3; qq = tid - i * 3;
    jlo = qq * 22; jhi = (jlo + 22 < NM) ? jlo + 22 : NM;
    st0 = STs[i][0]; st1 = STs[i][1]; st2 = STs[i][2]; hi = hs[i];
    rowz = gz || (mkm[i] == 0.f);
    float mx = -3.0e38f;
    for (int j = jlo; j < jhi; ++j) {
      float s = st0 * Ys1[j][0] + st1 * Ys1[j][1] + hi + gs[j] + wc;
      if (O == 3) s += st2 * Ys1[j][2];
      s = (rowz || mkm[j] == 0.f) ? -10000.f : ATT_SCALE * s;
      Pm[i][j] = s;
      mx = fmaxf(mx, s);
    }
    rmx[i][qq] = mx;
  }
  __syncthreads();
  if (act) {
    float mx = fmaxf(fmaxf(rmx[i][0], rmx[i][1]), rmx[i][2]);
    float sum = 0.f, y0 = 0.f, y1 = 0.f, y2 = 0.f;
    for (int j = jlo; j < jhi; ++j) {
      float pp = __expf(Pm[i][j] - mx);
      sum += pp; y0 += pp * Ys1[j][0]; y1 += pp * Ys1[j][1];
      if (O == 3) y2 += pp * Ys1[j][2];
    }
    rsum[i][qq] = sum; ry[i][qq][0] = y0; ry[i][qq][1] = y1; ry[i][qq][2] = y2;
  }
  __syncthreads();
  if (tid < NM) {
    int ii = tid;
    float sum = rsum[ii][0] + rsum[ii][1] + rsum[ii][2];
    float y0 = ry[ii][0][0] + ry[ii][1][0] + ry[ii][2][0];
    float y1 = ry[ii][0][1] + ry[ii][1][1] + ry[ii][2][1];
    float y2 = ry[ii][0][2] + ry[ii][1][2] + ry[ii][2][2];
    float inv = 1.f / sum;
    y0 *= inv; y1 *= inv; y2 *= inv;
    size_t ob = (((size_t)b * NVX + n) * NM + ii) * O;
    Y2[ob + 0] = y0; Y2[ob + 1] = y1;
    if (O == 3) Y2[ob + 2] = y2;
    Ys2[ii][0] = y0; Ys2[ii][1] = y1; Ys2[ii][2] = (O == 3) ? y2 : 0.f;
  }
  __syncthreads();
  const float* V2 = F + OF_V2;
  const float* dv = F + OF_dv;
  for (int d = tid; d < ND; d += 256) {
    float v0 = V2[d], v1 = V2[ND + d], v2 = (O == 3) ? V2[2 * ND + d] : 0.f;
    float mx = -3.0e38f;
    for (int j = 0; j < NM; ++j) {
      float s = Ys2[j][0] * v0 + Ys2[j][1] * v1;
      if (O == 3) s += Ys2[j][2] * v2;
      mx = fmaxf(mx, s);
    }
    size_t di = ((size_t)b * NVX + n) * ND + d;
    float nv = valb[di] + mx + dv[d];
    valb[di] = nv;
    vrow[d] = nv;
  }
  __syncthreads();
  const int wv = tid >> 6, lane = tid & 63;
  if (wv < O) {
    float acc = 0.f;
    for (int d = lane; d < ND; d += 64) acc += vrow[d] * lw[(size_t)wv * 2 * ND + ND + d];
    acc = wave_sum(acc);
    if (lane == 0) linV[((size_t)b * NVX + n) * O + wv] = acc;
  }
}

// fused key-update + linK per (b,m)
template <int O, int NVX>
__global__ __launch_bounds__(256) void k_kupd(
    const float* __restrict__ Y2, const float* __restrict__ F,
    float* __restrict__ keyb, const float* __restrict__ lw,
    float* __restrict__ linK)
{
  __shared__ float Ys[NVX][3];
  __shared__ float krow[ND];
  const int b = blockIdx.x >> 6, m = blockIdx.x & 63;
  const int tid = threadIdx.x;
  for (int u = tid; u < NVX * O; u += 256) {
    int j = u % NVX, o = u / NVX;
    Ys[j][o] = Y2[(((size_t)b * NVX + j) * NM + m) * O + o];
  }
  __syncthreads();
  const float* V2 = F + OF_V2;
  const float* dv = F + OF_dv;
  for (int d = tid; d < ND; d += 256) {
    float v0 = V2[d], v1 = V2[ND + d], v2 = (O == 3) ? V2[2 * ND + d] : 0.f;
    float mx = -3.0e38f;
    for (int j = 0; j < NVX; ++j) {
      float s = Ys[j][0] * v0 + Ys[j][1] * v1;
      if (O == 3) s += Ys[j][2] * v2;
      mx = fmaxf(mx, s);
    }
    size_t di = ((size_t)b * NM + m) * ND + d;
    float nv = keyb[di] + mx + dv[d];
    keyb[di] = nv;
    krow[d] = nv;
  }
  __syncthreads();
  const int wv = tid >> 6, lane = tid & 63;
  if (wv < O) {
    float acc = 0.f;
    for (int d = lane; d < ND; d += 64) acc += krow[d] * lw[(size_t)wv * 2 * ND + d];
    acc = wave_sum(acc);
    if (lane == 0) linK[((size_t)b * NM + m) * O + wv] = acc;
  }
}

// final bilinear with mask, register-ts + global Val
template <int O, int NVX>
__global__ __launch_bounds__(256) void k_bilfin(
    const float* __restrict__ T, const float* __restrict__ Val,
    const float* __restrict__ linK, const float* __restrict__ linV,
    const float* __restrict__ lb, const float* __restrict__ km,
    const float* __restrict__ vm, int vmOff, int vmStride,
    float* __restrict__ Out)
{
  const int b = blockIdx.x >> 6, m = blockIdx.x & 63;
  const int tid = threadIdx.x;
  const int lane = tid & 63, w = tid >> 6;
  float4 tsr[O][2];
#pragma unroll
  for (int o = 0; o < O; ++o) {
    const float4* trow = (const float4*)(T + (((size_t)b * O + o) * NM + m) * (size_t)ND);
    tsr[o][0] = trow[lane];
    tsr[o][1] = (lane < 56) ? trow[64 + lane] : make_float4(0.f, 0.f, 0.f, 0.f);
  }
  float lk[O];
#pragma unroll
  for (int o = 0; o < O; ++o) lk[o] = linK[((size_t)b * NM + m) * O + o] + lb[o];
  const float kmv = km[b * NM + m];
  for (int n = w; n < NVX; n += 4) {
    const float4* vrow = (const float4*)(Val + ((size_t)b * NVX + n) * (size_t)ND);
    float4 v0 = vrow[lane];
    float4 v1 = (lane < 56) ? vrow[64 + lane] : make_float4(0.f, 0.f, 0.f, 0.f);
    float a[3] = {0.f, 0.f, 0.f};
#pragma unroll
    for (int o = 0; o < O; ++o) {
      a[o] = v0.x * tsr[o][0].x + v0.y * tsr[o][0].y + v0.z * tsr[o][0].z + v0.w * tsr[o][0].w
           + v1.x * tsr[o][1].x + v1.y * tsr[o][1].y + v1.z * tsr[o][1].z + v1.w * tsr[o][1].w;
    }
#pragma unroll
    for (int o = 0; o < O; ++o) a[o] = wave_sum(a[o]);
    if (lane == 0) {
      float msk = kmv * vm[b * vmStride + vmOff + n];
      size_t ob = (((size_t)b * NM + m) * NVX + n) * O;
#pragma unroll
      for (int o = 0; o < O; ++o)
        Out[ob + o] = (a[o] + lk[o] + linV[((size_t)b * NVX + n) * O + o]) * msk;
    }
  }
}

// batched small matvec: Out[r,o] = X[r,:]·W[o, wOff:wOff+480]
struct SpCfg { const float* X; const float* W; float* Out; int R; int O; int wStride; int wOff; };
__global__ __launch_bounds__(256) void k_sproj6(
    SpCfg s0, SpCfg s1, SpCfg s2, SpCfg s3, SpCfg s4, SpCfg s5)
{
  int z = blockIdx.y;
  SpCfg c = (z == 0) ? s0 : (z == 1) ? s1 : (z == 2) ? s2 : (z == 3) ? s3 : (z == 4) ? s4 : s5;
  int gid = blockIdx.x * 4 + (threadIdx.x >> 6);
  if (gid >= c.R * c.O) return;
  int lane = threadIdx.x & 63;
  int r = gid / c.O, o = gid - r * c.O;
  const float* x = c.X + (size_t)r * ND;
  const float* wp = c.W + (size_t)o * c.wStride + c.wOff;
  float acc = 0.f;
  for (int d = lane; d < ND; d += 64) acc += x[d] * wp[d];
  acc = wave_sum(acc);
  if (lane == 0) c.Out[gid] = acc;
}

// ---------------- folds (batched over both paths via blockIdx.y) ----------------
struct FoldCfg { const float* fw; const float* fb; const float* qw; const float* qb; float* F; int O; };

__global__ __launch_bounds__(256) void k_fold1B(FoldCfg A, FoldCfg Bc)
{
  FoldCfg c = (blockIdx.y == 0) ? A : Bc;
  int O = c.O;
  int gid = blockIdx.x * 4 + (threadIdx.x >> 6);
  int lane = threadIdx.x & 63;
  if (gid >= 3 * ND) return;
  int part = gid / ND, cc0 = gid - part * ND;
  const float* qrow = c.qw + (size_t)(part * ND + cc0) * ND;
  float p0 = 0.f, p1 = 0.f, p2 = 0.f, cc = 0.f;
  for (int d = lane; d < ND; d += 64) {
    float q = qrow[d];
    p0 += c.fw[d * O + 0] * q;
    p1 += c.fw[d * O + 1] * q;
    if (O == 3) p2 += c.fw[d * O + 2] * q;
    cc += c.fb[d] * q;
  }
  p0 = wave_sum(p0); p1 = wave_sum(p1); p2 = wave_sum(p2); cc = wave_sum(cc);
  if (lane == 0) {
    c.F[OF_Pq + part * 1440 + 0 * ND + cc0] = p0;
    c.F[OF_Pq + part * 1440 + 1 * ND + cc0] = p1;
    c.F[OF_Pq + part * 1440 + 2 * ND + cc0] = (O == 3) ? p2 : 0.f;
    c.F[OF_cq + part * ND + cc0] = cc + c.qb[part * ND + cc0];
  }
}

__global__ __launch_bounds__(256) void k_fold2B(FoldCfg A, FoldCfg Bc)
{
  FoldCfg c = (blockIdx.y == 0) ? A : Bc;
  int O = c.O;
  float* F = c.F;
  int gid = blockIdx.x * 4 + (threadIdx.x >> 6);
  int lane = threadIdx.x & 63;
  if (gid < 3 * ND) {
    int part = gid / ND, cc0 = gid - part * ND;
    const float* qrow = c.qw + (size_t)(part * ND + cc0) * ND;
    const float* Pv = F + OF_Pq + 2 * 1440;
    const float* cv = F + OF_cq + 2 * ND;
    float p0 = 0.f, p1 = 0.f, p2 = 0.f, cc = 0.f;
    for (int d = lane; d < ND; d += 64) {
      float q = qrow[d];
      p0 += Pv[0 * ND + d] * q;
      p1 += Pv[1 * ND + d] * q;
      if (O == 3) p2 += Pv[2 * ND + d] * q;
      cc += cv[d] * q;
    }
    p0 = wave_sum(p0); p1 = wave_sum(p1); p2 = wave_sum(p2); cc = wave_sum(cc);
    if (lane == 0) {
      F[OF_Q2 + part * 1440 + 0 * ND + cc0] = p0;
      F[OF_Q2 + part * 1440 + 1 * ND + cc0] = p1;
      F[OF_Q2 + part * 1440 + 2 * ND + cc0] = (O == 3) ? p2 : 0.f;
      F[OF_dq + part * ND + cc0] = cc + c.qb[part * ND + cc0];
    }
  } else if (gid < 3 * ND + 16) {
    int s = gid - 3 * ND;
    const float* Pq = F + OF_Pq;
    const float* Pk = F + OF_Pq + 1440;
    const float* cq = F + OF_cq;
    const float* ck = F + OF_cq + ND;
    float acc = 0.f;
    if (s < 9) {
      int o = s / 3, op = s % 3;
      bool ok = (o < O) && (op < O);
      if (ok) for (int q = lane; q < ND; q += 64) acc += Pq[o * ND + q] * Pk[op * ND + q];
      acc = wave_sum(acc);
      if (lane == 0) F[OF_S + s] = ok ? acc : 0.f;
    } else if (s < 12) {
      int o = s - 9; bool ok = o < O;
      if (ok) for (int q = lane; q < ND; q += 64) acc += Pq[o * ND + q] * ck[q];
      acc = wave_sum(acc);
      if (lane == 0) F[OF_u + o] = ok ? acc : 0.f;
    } else if (s < 15) {
      int o = s - 12; bool ok = o < O;
      if (ok) for (int q = lane; q < ND; q += 64) acc += cq[q] * Pk[o * ND + q];
      acc = wave_sum(acc);
      if (lane == 0) F[OF_r + o] = ok ? acc : 0.f;
    } else {
      for (int q = lane; q < ND; q += 64) acc += cq[q] * ck[q];
      acc = wave_sum(acc);
      if (lane == 0) F[OF_w] = acc;
    }
  }
}

__global__ __launch_bounds__(256) void k_fold3B(FoldCfg A, FoldCfg Bc)
{
  FoldCfg c = (blockIdx.y == 0) ? A : Bc;
  int O = c.O;
  float* F = c.F;
  int s = blockIdx.x * 4 + (threadIdx.x >> 6);
  int lane = threadIdx.x & 63;
  if (s >= 16) return;
  const float* Q2 = F + OF_Q2;
  const float* K2 = F + OF_Q2 + 1440;
  const float* dq = F + OF_dq;
  const float* dk = F + OF_dq + ND;
  float acc = 0.f;
  if (s < 9) {
    int o = s / 3, op = s % 3;
    bool ok = (o < O) && (op < O);
    if (ok) for (int q = lane; q < ND; q += 64) acc += Q2[o * ND + q] * K2[op * ND + q];
    acc = wave_sum(acc);
    if (lane == 0) F[OF_S + 16 + s] = ok ? acc : 0.f;
  } else if (s < 12) {
    int o = s - 9; bool ok = o < O;
    if (ok) for (int q = lane; q < ND; q += 64) acc += Q2[o * ND + q] * dk[q];
    acc = wave_sum(acc);
    if (lane == 0) F[OF_u + 16 + o] = ok ? acc : 0.f;
  } else if (s < 15) {
    int o = s - 12; bool ok = o < O;
    if (ok) for (int q = lane; q < ND; q += 64) acc += dq[q] * K2[o * ND + q];
    acc = wave_sum(acc);
    if (lane == 0) F[OF_r + 16 + o] = ok ? acc : 0.f;
  } else {
    for (int q = lane; q < ND; q += 64) acc += dq[q] * dk[q];
    acc = wave_sum(acc);
    if (lane == 0) F[OF_w + 16] = acc;
  }
}

// argmax over 3 class logits at nv=0 -> km2
__global__ void k_type(const float* __restrict__ tl, const float* __restrict__ key_mask,
                       float* __restrict__ km2)
{
  int i = blockIdx.x * blockDim.x + threadIdx.x;
  if (i >= NB * NM) return;
  const float* p = tl + (size_t)i * NNV * 3;
  float l0 = p[0], l1 = p[1], l2 = p[2];
  int arg = 0;
  float best = l0;
  if (l1 > best) { best = l1; arg = 1; }
  if (l2 > best) { best = l2; arg = 2; }
  km2[i] = (key_mask[i] != 0.f && arg == 1) ? 1.f : 0.f;
}

__global__ void k_multi(const float* __restrict__ a, const float* __restrict__ bb,
                        const float* __restrict__ bc, float* __restrict__ out)
{
  int i = blockIdx.x * blockDim.x + threadIdx.x;
  if (i >= NB * NM * NM * 2) return;
  int c = i & 1;
  int t = i >> 1;
  int n = t % NM; t /= NM;
  int m = t % NM;
  int b = t / NM;
  out[i] = a[((size_t)b * NM + m) * 2 + c] + bb[((size_t)b * NM + n) * 2 + c] + bc[c];
}

template <int O, int NVX>
static void run_rounds(hipStream_t stream,
                       float* keyb, float* valb,
                       const float* kmp, const float* vmp, int vmOff, int vmStride,
                       const float* Wb, const float* lwp, const float* lbp,
                       float* fold, float* linK, float* linV,
                       float* tmp, float* Y1, float* Y2, float* outp)
{
  dim3 blk(256);
  for (int r = 0; r < 5; ++r) {
    k_tmp<O><<<dim3(15, NB), blk, 0, stream>>>(keyb, Wb, tmp);
    if (r < 4) {
      k_bilatt0<O, NVX><<<dim3(NB * NM), blk, 0, stream>>>(
          tmp, valb, linK, linV, lbp, fold, kmp, vmp, vmOff, vmStride, Y1);
      k_att1vupd<O, NVX><<<dim3(NB * NVX), blk, 0, stream>>>(
          Y1, Y2, fold, kmp, vmp, vmOff, vmStride, valb, lwp, linV);
      k_kupd<O, NVX><<<dim3(NB * NM), blk, 0, stream>>>(Y2, fold, keyb, lwp, linK);
    } else {
      k_bilfin<O, NVX><<<dim3(NB * NM), blk, 0, stream>>>(
          tmp, valb, linK, linV, lbp, kmp, vmp, vmOff, vmStride, outp);
    }
  }
}

extern "C" void kernel_launch(void* const* d_in, const int* in_sizes, int n_in,
                              void* d_out, int out_size, void* d_ws, size_t ws_size,
                              hipStream_t stream)
{
  const float* key        = (const float*)d_in[0];
  const float* value      = (const float*)d_in[1];
  const float* key_mask   = (const float*)d_in[2];
  const float* value_mask = (const float*)d_in[3];
  const float* w_kt = (const float*)d_in[4];  const float* b_kt = (const float*)d_in[5];
  const float* w_vt = (const float*)d_in[6];  const float* b_vt = (const float*)d_in[7];
  const float* w_km = (const float*)d_in[8];  const float* b_km = (const float*)d_in[9];
  const float* w_vm = (const float*)d_in[10]; const float* b_vm = (const float*)d_in[11];
  const float* w_ks = (const float*)d_in[12]; const float* b_ks = (const float*)d_in[13];
  const float* w_vs = (const float*)d_in[14]; const float* b_vs = (const float*)d_in[15];
  const float* bt_W = (const float*)d_in[16]; const float* bt_lw = (const float*)d_in[17];
  const float* bt_lb = (const float*)d_in[18];
  const float* bi_W = (const float*)d_in[19]; const float* bi_lw = (const float*)d_in[20];
  const float* bi_lb = (const float*)d_in[21];
  const float* w_ffnt = (const float*)d_in[22]; const float* b_ffnt = (const float*)d_in[23];
  const float* w_ffn  = (const float*)d_in[24]; const float* b_ffn  = (const float*)d_in[25];
  const float* qkvt_w = (const float*)d_in[26]; const float* qkvt_b = (const float*)d_in[27];
  const float* qkv_w  = (const float*)d_in[28]; const float* qkv_b  = (const float*)d_in[29];
  const float* w_cls  = (const float*)d_in[30]; const float* b_cls  = (const float*)d_in[31];

  float* ws = (float*)d_ws;
  size_t off = 0;
  float* kt_t  = ws + off; off += (size_t)NB * NM * ND;       // 983040
  float* vt_t  = ws + off; off += (size_t)NB * NNV * ND;      // 998400
  float* kt_s  = ws + off; off += (size_t)NB * NM * ND;
  float* vt_s  = ws + off; off += (size_t)NB * NM * ND;
  float* tmp   = ws + off; off += (size_t)NB * 3 * NM * ND;   // 2949120 (kmf/vmf overlap)
  float* Y1    = ws + off; off += (size_t)NB * NM * NNV * 3;
  float* Y2    = ws + off; off += (size_t)NB * NM * NNV * 3;
  float* linK_t = ws + off; off += (size_t)NB * NM * 3;
  float* linV_t = ws + off; off += (size_t)NB * NNV * 3;
  float* linK_s = ws + off; off += (size_t)NB * NM * 3;
  float* linV_s = ws + off; off += (size_t)NB * NM * 3;
  float* fold_t = ws + off; off += FOLD_SZ;
  float* fold_s = ws + off; off += FOLD_SZ;
  float* km2   = ws + off; off += (size_t)NB * NM;
  float* a2    = ws + off; off += (size_t)NB * NM * 2;
  float* b2    = ws + off; off += (size_t)NB * NM * 2;
  (void)off; (void)ws_size; (void)in_sizes; (void)n_in; (void)out_size;

  float* kmf = tmp;                               // projections done before rounds use tmp
  float* vmf = tmp + (size_t)NB * NM * ND;

  float* out_type   = (float*)d_out;                               // B*M*NV*3
  float* out_multi  = out_type + (size_t)NB * NM * NNV * 3;        // B*M*64*2
  float* out_single = out_multi + (size_t)NB * NM * NM * 2;        // B*M*64*2

  dim3 blk(256);

  // ---- all 6 big projections, one launch ----
  Proj6 P;
  P.c[0] = { key,   w_kt, b_kt, kt_t, NB * NM,  0, NM,  NM * NH };   // 32 panels
  P.c[1] = { value, w_vt, b_vt, vt_t, NB * NNV, 0, NNV, NNV * NH };  // 33 panels
  P.c[2] = { key,   w_ks, b_ks, kt_s, NB * NM,  0, NM,  NM * NH };   // 32
  P.c[3] = { value, w_vs, b_vs, vt_s, NB * NM,  1, NM,  NNV * NH };  // 32
  P.c[4] = { key,   w_km, b_km, kmf,  NB * NM,  0, NM,  NM * NH };   // 32
  P.c[5] = { value, w_vm, b_vm, vmf,  NB * NM,  1, NM,  NNV * NH };  // 32
  k_proj6<<<dim3(193 * 8), blk, 0, stream>>>(P, NH);

  // ---- folds for both paths (batched) ----
  FoldCfg ft = { w_ffnt, b_ffnt, qkvt_w, qkvt_b, fold_t, 3 };
  FoldCfg fs = { w_ffn,  b_ffn,  qkv_w,  qkv_b,  fold_s, 2 };
  k_fold1B<<<dim3(360, 2), blk, 0, stream>>>(ft, fs);
  k_fold2B<<<dim3(364, 2), blk, 0, stream>>>(ft, fs);
  k_fold3B<<<dim3(4, 2), blk, 0, stream>>>(ft, fs);

  // ---- all small matvecs (linK/linV inits for both paths, a2, b2), one launch ----
  SpCfg s0 = { kt_t, bt_lw, linK_t, NB * NM,  3, 2 * ND, 0 };
  SpCfg s1 = { vt_t, bt_lw, linV_t, NB * NNV, 3, 2 * ND, ND };
  SpCfg s2 = { kt_s, bi_lw, linK_s, NB * NM,  2, 2 * ND, 0 };
  SpCfg s3 = { vt_s, bi_lw, linV_s, NB * NM,  2, 2 * ND, ND };
  SpCfg s4 = { kmf,  w_cls, a2,     NB * NM,  2, 2 * ND, 0 };
  SpCfg s5 = { vmf,  w_cls, b2,     NB * NM,  2, 2 * ND, ND };
  k_sproj6<<<dim3((NB * NNV * 3 + 3) / 4, 6), blk, 0, stream>>>(s0, s1, s2, s3, s4, s5);

  // multi logits (independent of rounds)
  k_multi<<<dim3((NB * NM * NM * 2 + 255) / 256), blk, 0, stream>>>(a2, b2, b_cls, out_multi);

  // ---- type path rounds ----
  run_rounds<3, NNV>(stream, kt_t, vt_t, key_mask, value_mask, 0, NNV,
                     bt_W, bt_lw, bt_lb, fold_t, linK_t, linV_t,
                     tmp, Y1, Y2, out_type);

  // type decision -> km2
  k_type<<<dim3(8), blk, 0, stream>>>(out_type, key_mask, km2);

  // ---- single path rounds ----
  run_rounds<2, NM>(stream, kt_s, vt_s, km2, value_mask, 1, NNV,
                    bi_W, bi_lw, bi_lb, fold_s, linK_s, linV_s,
                    tmp, Y1, Y2, out_single);
}

// Round 5
// 1097.106 us; speedup vs baseline: 4.3527x; 1.3486x over previous
//
#include <hip/hip_runtime.h>
#include <math.h>

// ---------------- problem constants ----------------
constexpr int NB = 32;    // B
constexpr int NM = 64;    // M
constexpr int NNV = 65;   // NV
constexpr int NH = 960;   // H
constexpr int ND = 480;   // D
constexpr float ATT_SCALE = 0.045643546458763842f;  // D^-0.5

// fold-buffer offsets (floats). P blocks always strided for O=3.
constexpr int OF_Pq = 0;              // 3 parts x (3*480)
constexpr int OF_cq = 4320;           // 3 parts x 480
constexpr int OF_Q2 = 5760;           // 3 parts x (3*480)
constexpr int OF_V2 = OF_Q2 + 2*1440; // 8640
constexpr int OF_dq = 10080;          // 3 parts x 480
constexpr int OF_dv = OF_dq + 2*480;  // 11040
constexpr int OF_S  = 11520;          // 9  (S2 at +16)
constexpr int OF_u  = 11529;          // 3
constexpr int OF_r  = 11532;          // 3
constexpr int OF_w  = 11535;          // 1
constexpr int FOLD_SZ = 11552;

typedef float f32x4 __attribute__((ext_vector_type(4)));
typedef short s16x8 __attribute__((ext_vector_type(8)));

__device__ __forceinline__ float wave_sum(float v) {
#pragma unroll
  for (int d = 32; d; d >>= 1) v += __shfl_xor(v, d);
  return v;
}

__device__ __forceinline__ void split_bf16(float x, short& hi, short& lo) {
  union { float f; unsigned u; } a; a.f = x;
  unsigned uh = a.u + 0x7fffu + ((a.u >> 16) & 1u);
  hi = (short)(uh >> 16);
  union { unsigned u; float f; } b; b.u = ((unsigned)(unsigned short)hi) << 16;
  union { float f; unsigned u; } c; c.f = x - b.f;
  unsigned ul = c.u + 0x7fffu + ((c.u >> 16) & 1u);
  lo = (short)(ul >> 16);
}

// ---------------- MFMA split-bf16 projection GEMM (6 configs, XCD swizzled) ----------------
struct ProjCfg {
  const float* X; const float* W; const float* bias; float* C;
  int R; int x0; int rpb; int xbs;
};
struct Proj6 { ProjCfg c[6]; };

constexpr int KP = 40;   // padded k stride (ushorts): 80B rows, 16B aligned frag reads

// block = 64 rows x 48 cols, K=960. panels: c0:32,c1:33,c2..c5:32 -> 193 x 10 ctiles = 1930 blocks
__global__ __launch_bounds__(256) void k_projM(Proj6 P, int K)
{
  __shared__ unsigned short As_hi[64][KP], As_lo[64][KP];
  __shared__ unsigned short Bs_hi[48][KP], Bs_lo[48][KP];
  // bijective chunked XCD swizzle (total=1930, q=241, r=2)
  int p = blockIdx.x, total = gridDim.x;
  int q = total >> 3, r = total & 7;
  int xk = p & 7, idx = p >> 3;
  int lgc = (xk < r) ? (xk * (q + 1) + idx) : (r * (q + 1) + (xk - r) * q + idx);
  int mp = lgc / 10, nx = lgc - mp * 10;
  ProjCfg cfg; int my;
  if      (mp < 32)  { cfg = P.c[0]; my = mp; }
  else if (mp < 65)  { cfg = P.c[1]; my = mp - 32; }
  else if (mp < 97)  { cfg = P.c[2]; my = mp - 65; }
  else if (mp < 129) { cfg = P.c[3]; my = mp - 97; }
  else if (mp < 161) { cfg = P.c[4]; my = mp - 129; }
  else               { cfg = P.c[5]; my = mp - 161; }
  const int m0 = my * 64, n0 = nx * 48;
  const int tid = threadIdx.x;
  const int l6 = tid & 63, w = tid >> 6;
  const int lr = tid >> 2, kc = (tid & 3) * 8;   // stage coords
  const float* Arow = nullptr;
  {
    int rr = m0 + lr;
    if (rr < cfg.R) {
      int b = rr / cfg.rpb, r2 = rr - b * cfg.rpb;
      Arow = cfg.X + (size_t)b * cfg.xbs + (size_t)(cfg.x0 + r2) * K;
    }
  }
  const float* Brow = (lr < 48) ? (cfg.W + (size_t)(n0 + lr) * K) : nullptr;
  const int fr = l6 & 15, fk = (l6 >> 4) * 8;
  f32x4 acc0 = {0.f, 0.f, 0.f, 0.f}, acc1 = acc0, acc2 = acc0;
  for (int k0 = 0; k0 < K; k0 += 32) {
    float xs[8] = {0.f, 0.f, 0.f, 0.f, 0.f, 0.f, 0.f, 0.f};
    if (Arow) {
      float4 a0 = *(const float4*)(Arow + k0 + kc);
      float4 a1 = *(const float4*)(Arow + k0 + kc + 4);
      xs[0] = a0.x; xs[1] = a0.y; xs[2] = a0.z; xs[3] = a0.w;
      xs[4] = a1.x; xs[5] = a1.y; xs[6] = a1.z; xs[7] = a1.w;
    }
    s16x8 vh, vl;
#pragma unroll
    for (int e = 0; e < 8; ++e) { short h, lo2; split_bf16(xs[e], h, lo2); vh[e] = h; vl[e] = lo2; }
    *(s16x8*)&As_hi[lr][kc] = vh;
    *(s16x8*)&As_lo[lr][kc] = vl;
    if (Brow) {
      float4 b0 = *(const float4*)(Brow + k0 + kc);
      float4 b1 = *(const float4*)(Brow + k0 + kc + 4);
      float ys[8] = {b0.x, b0.y, b0.z, b0.w, b1.x, b1.y, b1.z, b1.w};
      s16x8 wh, wl;
#pragma unroll
      for (int e = 0; e < 8; ++e) { short h, lo2; split_bf16(ys[e], h, lo2); wh[e] = h; wl[e] = lo2; }
      *(s16x8*)&Bs_hi[lr][kc] = wh;
      *(s16x8*)&Bs_lo[lr][kc] = wl;
    }
    __syncthreads();
    s16x8 ah = *(const s16x8*)&As_hi[16 * w + fr][fk];
    s16x8 al = *(const s16x8*)&As_lo[16 * w + fr][fk];
    {
      s16x8 bh = *(const s16x8*)&Bs_hi[fr][fk];
      s16x8 bl = *(const s16x8*)&Bs_lo[fr][fk];
      acc0 = __builtin_amdgcn_mfma_f32_16x16x32_bf16(ah, bh, acc0, 0, 0, 0);
      acc0 = __builtin_amdgcn_mfma_f32_16x16x32_bf16(ah, bl, acc0, 0, 0, 0);
      acc0 = __builtin_amdgcn_mfma_f32_16x16x32_bf16(al, bh, acc0, 0, 0, 0);
    }
    {
      s16x8 bh = *(const s16x8*)&Bs_hi[16 + fr][fk];
      s16x8 bl = *(const s16x8*)&Bs_lo[16 + fr][fk];
      acc1 = __builtin_amdgcn_mfma_f32_16x16x32_bf16(ah, bh, acc1, 0, 0, 0);
      acc1 = __builtin_amdgcn_mfma_f32_16x16x32_bf16(ah, bl, acc1, 0, 0, 0);
      acc1 = __builtin_amdgcn_mfma_f32_16x16x32_bf16(al, bh, acc1, 0, 0, 0);
    }
    {
      s16x8 bh = *(const s16x8*)&Bs_hi[32 + fr][fk];
      s16x8 bl = *(const s16x8*)&Bs_lo[32 + fr][fk];
      acc2 = __builtin_amdgcn_mfma_f32_16x16x32_bf16(ah, bh, acc2, 0, 0, 0);
      acc2 = __builtin_amdgcn_mfma_f32_16x16x32_bf16(ah, bl, acc2, 0, 0, 0);
      acc2 = __builtin_amdgcn_mfma_f32_16x16x32_bf16(al, bh, acc2, 0, 0, 0);
    }
    __syncthreads();
  }
#pragma unroll
  for (int c = 0; c < 3; ++c) {
    f32x4 av = (c == 0) ? acc0 : (c == 1) ? acc1 : acc2;
    int n = n0 + 16 * c + fr;
    float bv = cfg.bias[n];
#pragma unroll
    for (int g = 0; g < 4; ++g) {
      int rr = m0 + 16 * w + (l6 >> 4) * 4 + g;
      if (rr < cfg.R) cfg.C[(size_t)rr * ND + n] = av[g] + bv;
    }
  }
}

// ---------------- MFMA split-bf16 tmp GEMM ----------------
// T[(b*O+o)][m,d2] = Key[b][m,:] @ W[o][:,d2]; grid (10 ctiles, O, NB)
__global__ __launch_bounds__(256) void k_tmpM(
    const float* __restrict__ Key, const float* __restrict__ W,
    float* __restrict__ T, int O)
{
  __shared__ unsigned short As_hi[64][KP], As_lo[64][KP];
  __shared__ unsigned short Bs_hi[48][KP], Bs_lo[48][KP];
  const int n0 = blockIdx.x * 48;
  const int o = blockIdx.y, b = blockIdx.z;
  const int tid = threadIdx.x;
  const int l6 = tid & 63, w = tid >> 6;
  const int lr = tid >> 2, kc = (tid & 3) * 8;
  const float* Arow = Key + (size_t)b * NM * ND + (size_t)lr * ND;
  const float* Wo = W + (size_t)o * ND * ND;
  const int fr = l6 & 15, fk = (l6 >> 4) * 8;
  f32x4 acc0 = {0.f, 0.f, 0.f, 0.f}, acc1 = acc0, acc2 = acc0;
  for (int k0 = 0; k0 < ND; k0 += 32) {
    {
      float4 a0 = *(const float4*)(Arow + k0 + kc);
      float4 a1 = *(const float4*)(Arow + k0 + kc + 4);
      float xs[8] = {a0.x, a0.y, a0.z, a0.w, a1.x, a1.y, a1.z, a1.w};
      s16x8 vh, vl;
#pragma unroll
      for (int e = 0; e < 8; ++e) { short h, lo2; split_bf16(xs[e], h, lo2); vh[e] = h; vl[e] = lo2; }
      *(s16x8*)&As_hi[lr][kc] = vh;
      *(s16x8*)&As_lo[lr][kc] = vl;
    }
    if (lr < 48) {   // transpose-stage B: Bs[n][k] <- W[k][n]
      s16x8 wh, wl;
#pragma unroll
      for (int e = 0; e < 8; ++e) {
        float x = Wo[(size_t)(k0 + kc + e) * ND + n0 + lr];
        short h, lo2; split_bf16(x, h, lo2); wh[e] = h; wl[e] = lo2;
      }
      *(s16x8*)&Bs_hi[lr][kc] = wh;
      *(s16x8*)&Bs_lo[lr][kc] = wl;
    }
    __syncthreads();
    s16x8 ah = *(const s16x8*)&As_hi[16 * w + fr][fk];
    s16x8 al = *(const s16x8*)&As_lo[16 * w + fr][fk];
    {
      s16x8 bh = *(const s16x8*)&Bs_hi[fr][fk];
      s16x8 bl = *(const s16x8*)&Bs_lo[fr][fk];
      acc0 = __builtin_amdgcn_mfma_f32_16x16x32_bf16(ah, bh, acc0, 0, 0, 0);
      acc0 = __builtin_amdgcn_mfma_f32_16x16x32_bf16(ah, bl, acc0, 0, 0, 0);
      acc0 = __builtin_amdgcn_mfma_f32_16x16x32_bf16(al, bh, acc0, 0, 0, 0);
    }
    {
      s16x8 bh = *(const s16x8*)&Bs_hi[16 + fr][fk];
      s16x8 bl = *(const s16x8*)&Bs_lo[16 + fr][fk];
      acc1 = __builtin_amdgcn_mfma_f32_16x16x32_bf16(ah, bh, acc1, 0, 0, 0);
      acc1 = __builtin_amdgcn_mfma_f32_16x16x32_bf16(ah, bl, acc1, 0, 0, 0);
      acc1 = __builtin_amdgcn_mfma_f32_16x16x32_bf16(al, bh, acc1, 0, 0, 0);
    }
    {
      s16x8 bh = *(const s16x8*)&Bs_hi[32 + fr][fk];
      s16x8 bl = *(const s16x8*)&Bs_lo[32 + fr][fk];
      acc2 = __builtin_amdgcn_mfma_f32_16x16x32_bf16(ah, bh, acc2, 0, 0, 0);
      acc2 = __builtin_amdgcn_mfma_f32_16x16x32_bf16(ah, bl, acc2, 0, 0, 0);
      acc2 = __builtin_amdgcn_mfma_f32_16x16x32_bf16(al, bh, acc2, 0, 0, 0);
    }
    __syncthreads();
  }
  float* C = T + ((size_t)(b * O + o) * NM) * ND;
#pragma unroll
  for (int c = 0; c < 3; ++c) {
    f32x4 av = (c == 0) ? acc0 : (c == 1) ? acc1 : acc2;
    int n = n0 + 16 * c + fr;
#pragma unroll
    for (int g = 0; g < 4; ++g) {
      int rr = 16 * w + (l6 >> 4) * 4 + g;
      C[(size_t)rr * ND + n] = av[g];
    }
  }
}

// fused bilinear + attention(MODE0) per (b,m) with parallel softmax
template <int O, int NVX>
__global__ __launch_bounds__(256) void k_bilatt0(
    const float* __restrict__ T, const float* __restrict__ Val,
    const float* __restrict__ linK, const float* __restrict__ linV,
    const float* __restrict__ lb, const float* __restrict__ F,
    const float* __restrict__ km, const float* __restrict__ vm,
    int vmOff, int vmStride, float* __restrict__ Y1)
{
  __shared__ float Ls[NVX][3];
  __shared__ float STs[NVX][3];
  __shared__ float hs[NVX], gs[NVX], mkj[NVX];
  __shared__ float Pm[NVX][66];
  __shared__ float rmx[NVX][3];
  __shared__ float rsum[NVX][3];
  __shared__ float ry[NVX][3][3];
  __shared__ float lvs[NVX][3];
  const int b = blockIdx.x >> 6, m = blockIdx.x & 63;
  const int tid = threadIdx.x;
  const int lane = tid & 63, w = tid >> 6;

  for (int j = tid; j < NVX; j += 256) {
    mkj[j] = vm[b * vmStride + vmOff + j];
#pragma unroll
    for (int o = 0; o < O; ++o) lvs[j][o] = linV[((size_t)b * NVX + j) * O + o];
  }
  float4 tsr[O][2];
#pragma unroll
  for (int o = 0; o < O; ++o) {
    const float4* trow = (const float4*)(T + (((size_t)b * O + o) * NM + m) * (size_t)ND);
    tsr[o][0] = trow[lane];
    tsr[o][1] = (lane < 56) ? trow[64 + lane] : make_float4(0.f, 0.f, 0.f, 0.f);
  }
  float lk[O];
#pragma unroll
  for (int o = 0; o < O; ++o) lk[o] = linK[((size_t)b * NM + m) * O + o] + lb[o];
  const float gm = km[b * NM + m];
  const bool gz = (gm == 0.f);

  for (int n = w; n < NVX; n += 4) {
    const float4* vrow = (const float4*)(Val + ((size_t)b * NVX + n) * (size_t)ND);
    float4 v0 = vrow[lane];
    float4 v1 = (lane < 56) ? vrow[64 + lane] : make_float4(0.f, 0.f, 0.f, 0.f);
    float a[3] = {0.f, 0.f, 0.f};
#pragma unroll
    for (int o = 0; o < O; ++o) {
      a[o] = v0.x * tsr[o][0].x + v0.y * tsr[o][0].y + v0.z * tsr[o][0].z + v0.w * tsr[o][0].w
           + v1.x * tsr[o][1].x + v1.y * tsr[o][1].y + v1.z * tsr[o][1].z + v1.w * tsr[o][1].w;
    }
#pragma unroll
    for (int o = 0; o < O; ++o) a[o] = wave_sum(a[o]);
    if (lane == 0) {
#pragma unroll
      for (int o = 0; o < O; ++o) Ls[n][o] = a[o] + lk[o] + lvs[n][o];
      if (O == 2) Ls[n][2] = 0.f;
    }
  }
  __syncthreads();
  const float* Sm = F + OF_S;
  const float u0 = F[OF_u], u1 = F[OF_u + 1], u2 = F[OF_u + 2];
  const float r0 = F[OF_r], r1 = F[OF_r + 1], r2 = F[OF_r + 2];
  const float wc = F[OF_w];
  if (tid < NVX) {
    int j = tid;
    float t0 = Ls[j][0], t1 = Ls[j][1], t2 = Ls[j][2];
    STs[j][0] = t0 * Sm[0] + t1 * Sm[3] + t2 * Sm[6];
    STs[j][1] = t0 * Sm[1] + t1 * Sm[4] + t2 * Sm[7];
    STs[j][2] = t0 * Sm[2] + t1 * Sm[5] + t2 * Sm[8];
    hs[j] = t0 * u0 + t1 * u1 + t2 * u2;
    gs[j] = t0 * r0 + t1 * r1 + t2 * r2;
  }
  __syncthreads();
  const bool act = tid < NVX * 3;
  int i = 0, qq = 0, jlo = 0, jhi = 0;
  float st0 = 0, st1 = 0, st2 = 0, hi = 0;
  bool rowz = true;
  if (act) {
    i = tid / 3; qq = tid - i * 3;
    jlo = qq * 22; jhi = (jlo + 22 < NVX) ? jlo + 22 : NVX;
    st0 = STs[i][0]; st1 = STs[i][1]; st2 = STs[i][2]; hi = hs[i];
    rowz = gz || (mkj[i] == 0.f);
    float mx = -3.0e38f;
    for (int j = jlo; j < jhi; ++j) {
      float s = st0 * Ls[j][0] + st1 * Ls[j][1] + hi + gs[j] + wc;
      if (O == 3) s += st2 * Ls[j][2];
      s = (rowz || mkj[j] == 0.f) ? -10000.f : ATT_SCALE * s;
      Pm[i][j] = s;
      mx = fmaxf(mx, s);
    }
    rmx[i][qq] = mx;
  }
  __syncthreads();
  if (act) {
    float mx = fmaxf(fmaxf(rmx[i][0], rmx[i][1]), rmx[i][2]);
    float sum = 0.f, y0 = 0.f, y1 = 0.f, y2 = 0.f;
    for (int j = jlo; j < jhi; ++j) {
      float pp = __expf(Pm[i][j] - mx);
      sum += pp; y0 += pp * Ls[j][0]; y1 += pp * Ls[j][1];
      if (O == 3) y2 += pp * Ls[j][2];
    }
    rsum[i][qq] = sum; ry[i][qq][0] = y0; ry[i][qq][1] = y1; ry[i][qq][2] = y2;
  }
  __syncthreads();
  if (tid < NVX) {
    int ii = tid;
    float sum = rsum[ii][0] + rsum[ii][1] + rsum[ii][2];
    float y0 = ry[ii][0][0] + ry[ii][1][0] + ry[ii][2][0];
    float y1 = ry[ii][0][1] + ry[ii][1][1] + ry[ii][2][1];
    float y2 = ry[ii][0][2] + ry[ii][1][2] + ry[ii][2][2];
    float inv = 1.f / sum;
    size_t ob = (((size_t)b * NM + m) * NVX + ii) * O;
    Y1[ob + 0] = y0 * inv;
    Y1[ob + 1] = y1 * inv;
    if (O == 3) Y1[ob + 2] = y2 * inv;
  }
}

// fused attention(MODE1) + value-update + linV per (b,n), parallel softmax
template <int O, int NVX>
__global__ __launch_bounds__(256) void k_att1vupd(
    const float* __restrict__ Y1, float* __restrict__ Y2,
    const float* __restrict__ F,
    const float* __restrict__ km, const float* __restrict__ vm,
    int vmOff, int vmStride,
    float* __restrict__ valb, const float* __restrict__ lw,
    float* __restrict__ linV)
{
  __shared__ float Ys1[NM][3];
  __shared__ float STs[NM][3];
  __shared__ float hs[NM], gs[NM], mkm[NM];
  __shared__ float Pm[NM][66];
  __shared__ float rmx[NM][3];
  __shared__ float rsum[NM][3];
  __shared__ float ry[NM][3][3];
  __shared__ float Ys2[NM][3];
  __shared__ float vrow[ND];
  const int b = blockIdx.x / NVX, n = blockIdx.x - b * NVX;
  const int tid = threadIdx.x;
  for (int u = tid; u < NM * O; u += 256) {
    int mm = u % NM, o = u / NM;
    Ys1[mm][o] = Y1[(((size_t)b * NM + mm) * NVX + n) * O + o];
  }
  if (tid < NM) {
    mkm[tid] = km[b * NM + tid];
    if (O == 2) Ys1[tid][2] = 0.f;
  }
  const float gm = vm[b * vmStride + vmOff + n];
  const bool gz = (gm == 0.f);
  __syncthreads();
  const float* Sm = F + OF_S + 16;
  const float u0 = F[OF_u + 16], u1 = F[OF_u + 17], u2 = F[OF_u + 18];
  const float r0 = F[OF_r + 16], r1 = F[OF_r + 17], r2 = F[OF_r + 18];
  const float wc = F[OF_w + 16];
  if (tid < NM) {
    int j = tid;
    float t0 = Ys1[j][0], t1 = Ys1[j][1], t2 = Ys1[j][2];
    STs[j][0] = t0 * Sm[0] + t1 * Sm[3] + t2 * Sm[6];
    STs[j][1] = t0 * Sm[1] + t1 * Sm[4] + t2 * Sm[7];
    STs[j][2] = t0 * Sm[2] + t1 * Sm[5] + t2 * Sm[8];
    hs[j] = t0 * u0 + t1 * u1 + t2 * u2;
    gs[j] = t0 * r0 + t1 * r1 + t2 * r2;
  }
  __syncthreads();
  const bool act = tid < NM * 3;
  int i = 0, qq = 0, jlo = 0, jhi = 0;
  float st0 = 0, st1 = 0, st2 = 0, hi = 0;
  bool rowz = true;
  if (act) {
    i = tid / 3; qq = tid - i * 3;
    jlo = qq * 22; jhi = (jlo + 22 < NM) ? jlo + 22 : NM;
    st0 = STs[i][0]; st1 = STs[i][1]; st2 = STs[i][2]; hi = hs[i];
    rowz = gz || (mkm[i] == 0.f);
    float mx = -3.0e38f;
    for (int j = jlo; j < jhi; ++j) {
      float s = st0 * Ys1[j][0] + st1 * Ys1[j][1] + hi + gs[j] + wc;
      if (O == 3) s += st2 * Ys1[j][2];
      s = (rowz || mkm[j] == 0.f) ? -10000.f : ATT_SCALE * s;
      Pm[i][j] = s;
      mx = fmaxf(mx, s);
    }
    rmx[i][qq] = mx;
  }
  __syncthreads();
  if (act) {
    float mx = fmaxf(fmaxf(rmx[i][0], rmx[i][1]), rmx[i][2]);
    float sum = 0.f, y0 = 0.f, y1 = 0.f, y2 = 0.f;
    for (int j = jlo; j < jhi; ++j) {
      float pp = __expf(Pm[i][j] - mx);
      sum += pp; y0 += pp * Ys1[j][0]; y1 += pp * Ys1[j][1];
      if (O == 3) y2 += pp * Ys1[j][2];
    }
    rsum[i][qq] = sum; ry[i][qq][0] = y0; ry[i][qq][1] = y1; ry[i][qq][2] = y2;
  }
  __syncthreads();
  if (tid < NM) {
    int ii = tid;
    float sum = rsum[ii][0] + rsum[ii][1] + rsum[ii][2];
    float y0 = ry[ii][0][0] + ry[ii][1][0] + ry[ii][2][0];
    float y1 = ry[ii][0][1] + ry[ii][1][1] + ry[ii][2][1];
    float y2 = ry[ii][0][2] + ry[ii][1][2] + ry[ii][2][2];
    float inv = 1.f / sum;
    y0 *= inv; y1 *= inv; y2 *= inv;
    size_t ob = (((size_t)b * NVX + n) * NM + ii) * O;
    Y2[ob + 0] = y0; Y2[ob + 1] = y1;
    if (O == 3) Y2[ob + 2] = y2;
    Ys2[ii][0] = y0; Ys2[ii][1] = y1; Ys2[ii][2] = (O == 3) ? y2 : 0.f;
  }
  __syncthreads();
  const float* V2 = F + OF_V2;
  const float* dv = F + OF_dv;
  for (int d = tid; d < ND; d += 256) {
    float v0 = V2[d], v1 = V2[ND + d], v2 = (O == 3) ? V2[2 * ND + d] : 0.f;
    float mx = -3.0e38f;
    for (int j = 0; j < NM; ++j) {
      float s = Ys2[j][0] * v0 + Ys2[j][1] * v1;
      if (O == 3) s += Ys2[j][2] * v2;
      mx = fmaxf(mx, s);
    }
    size_t di = ((size_t)b * NVX + n) * ND + d;
    float nv = valb[di] + mx + dv[d];
    valb[di] = nv;
    vrow[d] = nv;
  }
  __syncthreads();
  const int wv = tid >> 6, lane = tid & 63;
  if (wv < O) {
    float acc = 0.f;
    for (int d = lane; d < ND; d += 64) acc += vrow[d] * lw[(size_t)wv * 2 * ND + ND + d];
    acc = wave_sum(acc);
    if (lane == 0) linV[((size_t)b * NVX + n) * O + wv] = acc;
  }
}

// fused key-update + linK per (b,m)
template <int O, int NVX>
__global__ __launch_bounds__(256) void k_kupd(
    const float* __restrict__ Y2, const float* __restrict__ F,
    float* __restrict__ keyb, const float* __restrict__ lw,
    float* __restrict__ linK)
{
  __shared__ float Ys[NVX][3];
  __shared__ float krow[ND];
  const int b = blockIdx.x >> 6, m = blockIdx.x & 63;
  const int tid = threadIdx.x;
  for (int u = tid; u < NVX * O; u += 256) {
    int j = u % NVX, o = u / NVX;
    Ys[j][o] = Y2[(((size_t)b * NVX + j) * NM + m) * O + o];
  }
  __syncthreads();
  const float* V2 = F + OF_V2;
  const float* dv = F + OF_dv;
  for (int d = tid; d < ND; d += 256) {
    float v0 = V2[d], v1 = V2[ND + d], v2 = (O == 3) ? V2[2 * ND + d] : 0.f;
    float mx = -3.0e38f;
    for (int j = 0; j < NVX; ++j) {
      float s = Ys[j][0] * v0 + Ys[j][1] * v1;
      if (O == 3) s += Ys[j][2] * v2;
      mx = fmaxf(mx, s);
    }
    size_t di = ((size_t)b * NM + m) * ND + d;
    float nv = keyb[di] + mx + dv[d];
    keyb[di] = nv;
    krow[d] = nv;
  }
  __syncthreads();
  const int wv = tid >> 6, lane = tid & 63;
  if (wv < O) {
    float acc = 0.f;
    for (int d = lane; d < ND; d += 64) acc += krow[d] * lw[(size_t)wv * 2 * ND + d];
    acc = wave_sum(acc);
    if (lane == 0) linK[((size_t)b * NM + m) * O + wv] = acc;
  }
}

// final bilinear with mask, register-ts + global Val
template <int O, int NVX>
__global__ __launch_bounds__(256) void k_bilfin(
    const float* __restrict__ T, const float* __restrict__ Val,
    const float* __restrict__ linK, const float* __restrict__ linV,
    const float* __restrict__ lb, const float* __restrict__ km,
    const float* __restrict__ vm, int vmOff, int vmStride,
    float* __restrict__ Out)
{
  const int b = blockIdx.x >> 6, m = blockIdx.x & 63;
  const int tid = threadIdx.x;
  const int lane = tid & 63, w = tid >> 6;
  float4 tsr[O][2];
#pragma unroll
  for (int o = 0; o < O; ++o) {
    const float4* trow = (const float4*)(T + (((size_t)b * O + o) * NM + m) * (size_t)ND);
    tsr[o][0] = trow[lane];
    tsr[o][1] = (lane < 56) ? trow[64 + lane] : make_float4(0.f, 0.f, 0.f, 0.f);
  }
  float lk[O];
#pragma unroll
  for (int o = 0; o < O; ++o) lk[o] = linK[((size_t)b * NM + m) * O + o] + lb[o];
  const float kmv = km[b * NM + m];
  for (int n = w; n < NVX; n += 4) {
    const float4* vrow = (const float4*)(Val + ((size_t)b * NVX + n) * (size_t)ND);
    float4 v0 = vrow[lane];
    float4 v1 = (lane < 56) ? vrow[64 + lane] : make_float4(0.f, 0.f, 0.f, 0.f);
    float a[3] = {0.f, 0.f, 0.f};
#pragma unroll
    for (int o = 0; o < O; ++o) {
      a[o] = v0.x * tsr[o][0].x + v0.y * tsr[o][0].y + v0.z * tsr[o][0].z + v0.w * tsr[o][0].w
           + v1.x * tsr[o][1].x + v1.y * tsr[o][1].y + v1.z * tsr[o][1].z + v1.w * tsr[o][1].w;
    }
#pragma unroll
    for (int o = 0; o < O; ++o) a[o] = wave_sum(a[o]);
    if (lane == 0) {
      float msk = kmv * vm[b * vmStride + vmOff + n];
      size_t ob = (((size_t)b * NM + m) * NVX + n) * O;
#pragma unroll
      for (int o = 0; o < O; ++o)
        Out[ob + o] = (a[o] + lk[o] + linV[((size_t)b * NVX + n) * O + o]) * msk;
    }
  }
}

// batched small matvec: Out[r,o] = X[r,:]·W[o, wOff:wOff+480]
struct SpCfg { const float* X; const float* W; float* Out; int R; int O; int wStride; int wOff; };
__global__ __launch_bounds__(256) void k_sproj6(
    SpCfg s0, SpCfg s1, SpCfg s2, SpCfg s3, SpCfg s4, SpCfg s5)
{
  int z = blockIdx.y;
  SpCfg c = (z == 0) ? s0 : (z == 1) ? s1 : (z == 2) ? s2 : (z == 3) ? s3 : (z == 4) ? s4 : s5;
  int gid = blockIdx.x * 4 + (threadIdx.x >> 6);
  if (gid >= c.R * c.O) return;
  int lane = threadIdx.x & 63;
  int r = gid / c.O, o = gid - r * c.O;
  const float* x = c.X + (size_t)r * ND;
  const float* wp = c.W + (size_t)o * c.wStride + c.wOff;
  float acc = 0.f;
  for (int d = lane; d < ND; d += 64) acc += x[d] * wp[d];
  acc = wave_sum(acc);
  if (lane == 0) c.Out[gid] = acc;
}

// ---------------- folds (batched over both paths via blockIdx.y) ----------------
struct FoldCfg { const float* fw; const float* fb; const float* qw; const float* qb; float* F; int O; };

__global__ __launch_bounds__(256) void k_fold1B(FoldCfg A, FoldCfg Bc)
{
  FoldCfg c = (blockIdx.y == 0) ? A : Bc;
  int O = c.O;
  int gid = blockIdx.x * 4 + (threadIdx.x >> 6);
  int lane = threadIdx.x & 63;
  if (gid >= 3 * ND) return;
  int part = gid / ND, cc0 = gid - part * ND;
  const float* qrow = c.qw + (size_t)(part * ND + cc0) * ND;
  float p0 = 0.f, p1 = 0.f, p2 = 0.f, cc = 0.f;
  for (int d = lane; d < ND; d += 64) {
    float q = qrow[d];
    p0 += c.fw[d * O + 0] * q;
    p1 += c.fw[d * O + 1] * q;
    if (O == 3) p2 += c.fw[d * O + 2] * q;
    cc += c.fb[d] * q;
  }
  p0 = wave_sum(p0); p1 = wave_sum(p1); p2 = wave_sum(p2); cc = wave_sum(cc);
  if (lane == 0) {
    c.F[OF_Pq + part * 1440 + 0 * ND + cc0] = p0;
    c.F[OF_Pq + part * 1440 + 1 * ND + cc0] = p1;
    c.F[OF_Pq + part * 1440 + 2 * ND + cc0] = (O == 3) ? p2 : 0.f;
    c.F[OF_cq + part * ND + cc0] = cc + c.qb[part * ND + cc0];
  }
}

__global__ __launch_bounds__(256) void k_fold2B(FoldCfg A, FoldCfg Bc)
{
  FoldCfg c = (blockIdx.y == 0) ? A : Bc;
  int O = c.O;
  float* F = c.F;
  int gid = blockIdx.x * 4 + (threadIdx.x >> 6);
  int lane = threadIdx.x & 63;
  if (gid < 3 * ND) {
    int part = gid / ND, cc0 = gid - part * ND;
    const float* qrow = c.qw + (size_t)(part * ND + cc0) * ND;
    const float* Pv = F + OF_Pq + 2 * 1440;
    const float* cv = F + OF_cq + 2 * ND;
    float p0 = 0.f, p1 = 0.f, p2 = 0.f, cc = 0.f;
    for (int d = lane; d < ND; d += 64) {
      float q = qrow[d];
      p0 += Pv[0 * ND + d] * q;
      p1 += Pv[1 * ND + d] * q;
      if (O == 3) p2 += Pv[2 * ND + d] * q;
      cc += cv[d] * q;
    }
    p0 = wave_sum(p0); p1 = wave_sum(p1); p2 = wave_sum(p2); cc = wave_sum(cc);
    if (lane == 0) {
      F[OF_Q2 + part * 1440 + 0 * ND + cc0] = p0;
      F[OF_Q2 + part * 1440 + 1 * ND + cc0] = p1;
      F[OF_Q2 + part * 1440 + 2 * ND + cc0] = (O == 3) ? p2 : 0.f;
      F[OF_dq + part * ND + cc0] = cc + c.qb[part * ND + cc0];
    }
  } else if (gid < 3 * ND + 16) {
    int s = gid - 3 * ND;
    const float* Pq = F + OF_Pq;
    const float* Pk = F + OF_Pq + 1440;
    const float* cq = F + OF_cq;
    const float* ck = F + OF_cq + ND;
    float acc = 0.f;
    if (s < 9) {
      int o = s / 3, op = s % 3;
      bool ok = (o < O) && (op < O);
      if (ok) for (int q = lane; q < ND; q += 64) acc += Pq[o * ND + q] * Pk[op * ND + q];
      acc = wave_sum(acc);
      if (lane == 0) F[OF_S + s] = ok ? acc : 0.f;
    } else if (s < 12) {
      int o = s - 9; bool ok = o < O;
      if (ok) for (int q = lane; q < ND; q += 64) acc += Pq[o * ND + q] * ck[q];
      acc = wave_sum(acc);
      if (lane == 0) F[OF_u + o] = ok ? acc : 0.f;
    } else if (s < 15) {
      int o = s - 12; bool ok = o < O;
      if (ok) for (int q = lane; q < ND; q += 64) acc += cq[q] * Pk[o * ND + q];
      acc = wave_sum(acc);
      if (lane == 0) F[OF_r + o] = ok ? acc : 0.f;
    } else {
      for (int q = lane; q < ND; q += 64) acc += cq[q] * ck[q];
      acc = wave_sum(acc);
      if (lane == 0) F[OF_w] = acc;
    }
  }
}

__global__ __launch_bounds__(256) void k_fold3B(FoldCfg A, FoldCfg Bc)
{
  FoldCfg c = (blockIdx.y == 0) ? A : Bc;
  int O = c.O;
  float* F = c.F;
  int s = blockIdx.x * 4 + (threadIdx.x >> 6);
  int lane = threadIdx.x & 63;
  if (s >= 16) return;
  const float* Q2 = F + OF_Q2;
  const float* K2 = F + OF_Q2 + 1440;
  const float* dq = F + OF_dq;
  const float* dk = F + OF_dq + ND;
  float acc = 0.f;
  if (s < 9) {
    int o = s / 3, op = s % 3;
    bool ok = (o < O) && (op < O);
    if (ok) for (int q = lane; q < ND; q += 64) acc += Q2[o * ND + q] * K2[op * ND + q];
    acc = wave_sum(acc);
    if (lane == 0) F[OF_S + 16 + s] = ok ? acc : 0.f;
  } else if (s < 12) {
    int o = s - 9; bool ok = o < O;
    if (ok) for (int q = lane; q < ND; q += 64) acc += Q2[o * ND + q] * dk[q];
    acc = wave_sum(acc);
    if (lane == 0) F[OF_u + 16 + o] = ok ? acc : 0.f;
  } else if (s < 15) {
    int o = s - 12; bool ok = o < O;
    if (ok) for (int q = lane; q < ND; q += 64) acc += dq[q] * K2[o * ND + q];
    acc = wave_sum(acc);
    if (lane == 0) F[OF_r + 16 + o] = ok ? acc : 0.f;
  } else {
    for (int q = lane; q < ND; q += 64) acc += dq[q] * dk[q];
    acc = wave_sum(acc);
    if (lane == 0) F[OF_w + 16] = acc;
  }
}

// argmax over 3 class logits at nv=0 -> km2
__global__ void k_type(const float* __restrict__ tl, const float* __restrict__ key_mask,
                       float* __restrict__ km2)
{
  int i = blockIdx.x * blockDim.x + threadIdx.x;
  if (i >= NB * NM) return;
  const float* p = tl + (size_t)i * NNV * 3;
  float l0 = p[0], l1 = p[1], l2 = p[2];
  int arg = 0;
  float best = l0;
  if (l1 > best) { best = l1; arg = 1; }
  if (l2 > best) { best = l2; arg = 2; }
  km2[i] = (key_mask[i] != 0.f && arg == 1) ? 1.f : 0.f;
}

__global__ void k_multi(const float* __restrict__ a, const float* __restrict__ bb,
                        const float* __restrict__ bc, float* __restrict__ out)
{
  int i = blockIdx.x * blockDim.x + threadIdx.x;
  if (i >= NB * NM * NM * 2) return;
  int c = i & 1;
  int t = i >> 1;
  int n = t % NM; t /= NM;
  int m = t % NM;
  int b = t / NM;
  out[i] = a[((size_t)b * NM + m) * 2 + c] + bb[((size_t)b * NM + n) * 2 + c] + bc[c];
}

template <int O, int NVX>
static void run_rounds(hipStream_t stream,
                       float* keyb, float* valb,
                       const float* kmp, const float* vmp, int vmOff, int vmStride,
                       const float* Wb, const float* lwp, const float* lbp,
                       float* fold, float* linK, float* linV,
                       float* tmp, float* Y1, float* Y2, float* outp)
{
  dim3 blk(256);
  for (int r = 0; r < 5; ++r) {
    k_tmpM<<<dim3(10, O, NB), blk, 0, stream>>>(keyb, Wb, tmp, O);
    if (r < 4) {
      k_bilatt0<O, NVX><<<dim3(NB * NM), blk, 0, stream>>>(
          tmp, valb, linK, linV, lbp, fold, kmp, vmp, vmOff, vmStride, Y1);
      k_att1vupd<O, NVX><<<dim3(NB * NVX), blk, 0, stream>>>(
          Y1, Y2, fold, kmp, vmp, vmOff, vmStride, valb, lwp, linV);
      k_kupd<O, NVX><<<dim3(NB * NM), blk, 0, stream>>>(Y2, fold, keyb, lwp, linK);
    } else {
      k_bilfin<O, NVX><<<dim3(NB * NM), blk, 0, stream>>>(
          tmp, valb, linK, linV, lbp, kmp, vmp, vmOff, vmStride, outp);
    }
  }
}

extern "C" void kernel_launch(void* const* d_in, const int* in_sizes, int n_in,
                              void* d_out, int out_size, void* d_ws, size_t ws_size,
                              hipStream_t stream)
{
  const float* key        = (const float*)d_in[0];
  const float* value      = (const float*)d_in[1];
  const float* key_mask   = (const float*)d_in[2];
  const float* value_mask = (const float*)d_in[3];
  const float* w_kt = (const float*)d_in[4];  const float* b_kt = (const float*)d_in[5];
  const float* w_vt = (const float*)d_in[6];  const float* b_vt = (const float*)d_in[7];
  const float* w_km = (const float*)d_in[8];  const float* b_km = (const float*)d_in[9];
  const float* w_vm = (const float*)d_in[10]; const float* b_vm = (const float*)d_in[11];
  const float* w_ks = (const float*)d_in[12]; const float* b_ks = (const float*)d_in[13];
  const float* w_vs = (const float*)d_in[14]; const float* b_vs = (const float*)d_in[15];
  const float* bt_W = (const float*)d_in[16]; const float* bt_lw = (const float*)d_in[17];
  const float* bt_lb = (const float*)d_in[18];
  const float* bi_W = (const float*)d_in[19]; const float* bi_lw = (const float*)d_in[20];
  const float* bi_lb = (const float*)d_in[21];
  const float* w_ffnt = (const float*)d_in[22]; const float* b_ffnt = (const float*)d_in[23];
  const float* w_ffn  = (const float*)d_in[24]; const float* b_ffn  = (const float*)d_in[25];
  const float* qkvt_w = (const float*)d_in[26]; const float* qkvt_b = (const float*)d_in[27];
  const float* qkv_w  = (const float*)d_in[28]; const float* qkv_b  = (const float*)d_in[29];
  const float* w_cls  = (const float*)d_in[30]; const float* b_cls  = (const float*)d_in[31];

  float* ws = (float*)d_ws;
  size_t off = 0;
  float* kt_t  = ws + off; off += (size_t)NB * NM * ND;
  float* vt_t  = ws + off; off += (size_t)NB * NNV * ND;
  float* kt_s  = ws + off; off += (size_t)NB * NM * ND;
  float* vt_s  = ws + off; off += (size_t)NB * NM * ND;
  float* tmp   = ws + off; off += (size_t)NB * 3 * NM * ND;
  float* Y1    = ws + off; off += (size_t)NB * NM * NNV * 3;
  float* Y2    = ws + off; off += (size_t)NB * NM * NNV * 3;
  float* linK_t = ws + off; off += (size_t)NB * NM * 3;
  float* linV_t = ws + off; off += (size_t)NB * NNV * 3;
  float* linK_s = ws + off; off += (size_t)NB * NM * 3;
  float* linV_s = ws + off; off += (size_t)NB * NM * 3;
  float* fold_t = ws + off; off += FOLD_SZ;
  float* fold_s = ws + off; off += FOLD_SZ;
  float* km2   = ws + off; off += (size_t)NB * NM;
  float* a2    = ws + off; off += (size_t)NB * NM * 2;
  float* b2    = ws + off; off += (size_t)NB * NM * 2;
  (void)off; (void)ws_size; (void)in_sizes; (void)n_in; (void)out_size;

  float* kmf = tmp;                               // projections done before rounds use tmp
  float* vmf = tmp + (size_t)NB * NM * ND;

  float* out_type   = (float*)d_out;                               // B*M*NV*3
  float* out_multi  = out_type + (size_t)NB * NM * NNV * 3;        // B*M*64*2
  float* out_single = out_multi + (size_t)NB * NM * NM * 2;        // B*M*64*2

  dim3 blk(256);

  // ---- all 6 big projections, one MFMA launch ----
  Proj6 P;
  P.c[0] = { key,   w_kt, b_kt, kt_t, NB * NM,  0, NM,  NM * NH };   // 32 panels
  P.c[1] = { value, w_vt, b_vt, vt_t, NB * NNV, 0, NNV, NNV * NH };  // 33 panels
  P.c[2] = { key,   w_ks, b_ks, kt_s, NB * NM,  0, NM,  NM * NH };   // 32
  P.c[3] = { value, w_vs, b_vs, vt_s, NB * NM,  1, NM,  NNV * NH };  // 32
  P.c[4] = { key,   w_km, b_km, kmf,  NB * NM,  0, NM,  NM * NH };   // 32
  P.c[5] = { value, w_vm, b_vm, vmf,  NB * NM,  1, NM,  NNV * NH };  // 32
  k_projM<<<dim3(193 * 10), blk, 0, stream>>>(P, NH);

  // ---- folds for both paths (batched) ----
  FoldCfg ft = { w_ffnt, b_ffnt, qkvt_w, qkvt_b, fold_t, 3 };
  FoldCfg fs = { w_ffn,  b_ffn,  qkv_w,  qkv_b,  fold_s, 2 };
  k_fold1B<<<dim3(360, 2), blk, 0, stream>>>(ft, fs);
  k_fold2B<<<dim3(364, 2), blk, 0, stream>>>(ft, fs);
  k_fold3B<<<dim3(4, 2), blk, 0, stream>>>(ft, fs);

  // ---- all small matvecs, one launch ----
  SpCfg s0 = { kt_t, bt_lw, linK_t, NB * NM,  3, 2 * ND, 0 };
  SpCfg s1 = { vt_t, bt_lw, linV_t, NB * NNV, 3, 2 * ND, ND };
  SpCfg s2 = { kt_s, bi_lw, linK_s, NB * NM,  2, 2 * ND, 0 };
  SpCfg s3 = { vt_s, bi_lw, linV_s, NB * NM,  2, 2 * ND, ND };
  SpCfg s4 = { kmf,  w_cls, a2,     NB * NM,  2, 2 * ND, 0 };
  SpCfg s5 = { vmf,  w_cls, b2,     NB * NM,  2, 2 * ND, ND };
  k_sproj6<<<dim3((NB * NNV * 3 + 3) / 4, 6), blk, 0, stream>>>(s0, s1, s2, s3, s4, s5);

  // multi logits (independent of rounds)
  k_multi<<<dim3((NB * NM * NM * 2 + 255) / 256), blk, 0, stream>>>(a2, b2, b_cls, out_multi);

  // ---- type path rounds ----
  run_rounds<3, NNV>(stream, kt_t, vt_t, key_mask, value_mask, 0, NNV,
                     bt_W, bt_lw, bt_lb, fold_t, linK_t, linV_t,
                     tmp, Y1, Y2, out_type);

  // type decision -> km2
  k_type<<<dim3(8), blk, 0, stream>>>(out_type, key_mask, km2);

  // ---- single path rounds ----
  run_rounds<2, NM>(stream, kt_s, vt_s, km2, value_mask, 1, NNV,
                    bi_W, bi_lw, bi_lb, fold_s, linK_s, linV_s,
                    tmp, Y1, Y2, out_single);
}